// Round 2
// baseline (5739.454 us; speedup 1.0000x reference)
//
#include <hip/hip_runtime.h>

#define D 128
#define BM 64
#define BN_EPS 1e-5f

// ---------------------------------------------------------------------------
// Scatter-add aggregation: agg[dst] += h[src] over all edges.
// One thread per (edge, 4-float chunk): coalesced float4 gather (512B/edge),
// 4 fp32 atomics to agg. NOTE: edge_index arrives as int32 (harness converts
// integer inputs to int) — reading it as int64 was round-1's fault.
// ---------------------------------------------------------------------------
__global__ __launch_bounds__(256) void gin_scatter(
    const float* __restrict__ h,
    const int* __restrict__ src,
    const int* __restrict__ dst,
    float* __restrict__ agg, int E)
{
    int idx = blockIdx.x * 256 + threadIdx.x;
    if (idx >= E * 32) return;
    int e = idx >> 5;
    int c = (idx & 31) << 2;
    int s = src[e];
    int d = dst[e];
    float4 v = *(const float4*)(h + (size_t)s * D + c);
    float* a = agg + (size_t)d * D + c;
    atomicAdd(a + 0, v.x);
    atomicAdd(a + 1, v.y);
    atomicAdd(a + 2, v.z);
    atomicAdd(a + 3, v.w);
}

// ---------------------------------------------------------------------------
// Block GEMM helper: acc[8][4] = U[64][128] @ W[128][128] + bias, where U is
// already staged in LDS and W is streamed through LDS in K=32 chunks.
// Thread (tr=tid>>5, tc=tid&31) owns rows tr*8..+7, cols tc*4..+3.
// ---------------------------------------------------------------------------
__device__ __forceinline__ void block_gemm(
    const float* __restrict__ Wl, const float* __restrict__ bias,
    float (*U)[D + 4], float (*Wc)[D],
    int tid, int tr, int tc, float acc[8][4])
{
    float4 bv = *(const float4*)(bias + tc * 4);
#pragma unroll
    for (int r = 0; r < 8; ++r) {
        acc[r][0] = bv.x; acc[r][1] = bv.y; acc[r][2] = bv.z; acc[r][3] = bv.w;
    }
#pragma unroll 1
    for (int kb = 0; kb < 4; ++kb) {
        // stage W rows [kb*32, kb*32+32) into LDS: 4096 floats, 4 float4/thread
#pragma unroll
        for (int i = 0; i < 4; ++i) {
            int f4 = tid + 256 * i;
            int kr = f4 >> 5;
            int c  = (f4 & 31) << 2;
            *(float4*)&Wc[kr][c] = *(const float4*)(Wl + (size_t)(kb * 32 + kr) * D + c);
        }
        __syncthreads();
#pragma unroll
        for (int k4 = 0; k4 < 8; ++k4) {
            float4 wv0 = *(const float4*)&Wc[k4 * 4 + 0][tc * 4];
            float4 wv1 = *(const float4*)&Wc[k4 * 4 + 1][tc * 4];
            float4 wv2 = *(const float4*)&Wc[k4 * 4 + 2][tc * 4];
            float4 wv3 = *(const float4*)&Wc[k4 * 4 + 3][tc * 4];
#pragma unroll
            for (int r = 0; r < 8; ++r) {
                float4 uv = *(const float4*)&U[tr * 8 + r][kb * 32 + k4 * 4];
                acc[r][0] = fmaf(uv.x, wv0.x, fmaf(uv.y, wv1.x, fmaf(uv.z, wv2.x, fmaf(uv.w, wv3.x, acc[r][0]))));
                acc[r][1] = fmaf(uv.x, wv0.y, fmaf(uv.y, wv1.y, fmaf(uv.z, wv2.y, fmaf(uv.w, wv3.y, acc[r][1]))));
                acc[r][2] = fmaf(uv.x, wv0.z, fmaf(uv.y, wv1.z, fmaf(uv.z, wv2.z, fmaf(uv.w, wv3.z, acc[r][2]))));
                acc[r][3] = fmaf(uv.x, wv0.w, fmaf(uv.y, wv1.w, fmaf(uv.z, wv2.w, fmaf(uv.w, wv3.w, acc[r][3]))));
            }
        }
        __syncthreads();
    }
}

// ---------------------------------------------------------------------------
// Fused per-layer MLP: z=(1+eps)*h+agg; z=bn1(relu(z@W1+b1)); h'=relu(bn2(z@W2+b2))
// Each block owns 64 rows end-to-end: intermediate activation stays in LDS.
// Safe to run in place (hout == hin): each block reads only its own rows
// before writing them.
// ---------------------------------------------------------------------------
__global__ __launch_bounds__(256) void gin_mlp(
    const float* __restrict__ hin, const float* __restrict__ agg,
    const float* __restrict__ W1, const float* __restrict__ b1,
    const float* __restrict__ g1, const float* __restrict__ be1,
    const float* __restrict__ m1, const float* __restrict__ v1,
    const float* __restrict__ W2, const float* __restrict__ b2,
    const float* __restrict__ g2, const float* __restrict__ be2,
    const float* __restrict__ m2, const float* __restrict__ v2,
    const float* __restrict__ eps, int layer, int N,
    float* __restrict__ hout)
{
    __shared__ float U[BM][D + 4];   // 64x132 fp32 = 33.8 KB (pad kills bank conflicts)
    __shared__ float Wc[32][D];      // 16 KB weight chunk

    const int tid  = threadIdx.x;
    const int tc   = tid & 31;
    const int tr   = tid >> 5;
    const int row0 = blockIdx.x * BM;

    const float epsv = 1.0f + eps[layer];
    const float* W1l = W1 + (size_t)layer * D * D;
    const float* W2l = W2 + (size_t)layer * D * D;

    // ---- stage U = (1+eps)*h + agg ----
#pragma unroll
    for (int i = 0; i < 8; ++i) {
        int f4 = tid + 256 * i;        // 0..2047 float4 slots
        int r  = f4 >> 5;
        int c  = (f4 & 31) << 2;
        int grow = row0 + r;
        float4 u = make_float4(0.f, 0.f, 0.f, 0.f);
        if (grow < N) {
            float4 hv = *(const float4*)(hin + (size_t)grow * D + c);
            float4 av = *(const float4*)(agg + (size_t)grow * D + c);
            u.x = fmaf(epsv, hv.x, av.x);
            u.y = fmaf(epsv, hv.y, av.y);
            u.z = fmaf(epsv, hv.z, av.z);
            u.w = fmaf(epsv, hv.w, av.w);
        }
        *(float4*)&U[r][c] = u;
    }
    __syncthreads();

    float acc[8][4];

    // ---- GEMM1 + ReLU + BN1, result back into U ----
    block_gemm(W1l, b1 + layer * D, U, Wc, tid, tr, tc, acc);
    {
        float4 gv = *(const float4*)(g1  + layer * D + tc * 4);
        float4 bv = *(const float4*)(be1 + layer * D + tc * 4);
        float4 mv = *(const float4*)(m1  + layer * D + tc * 4);
        float4 vv = *(const float4*)(v1  + layer * D + tc * 4);
        float4 s, t;
        s.x = gv.x * rsqrtf(vv.x + BN_EPS); t.x = bv.x - mv.x * s.x;
        s.y = gv.y * rsqrtf(vv.y + BN_EPS); t.y = bv.y - mv.y * s.y;
        s.z = gv.z * rsqrtf(vv.z + BN_EPS); t.z = bv.z - mv.z * s.z;
        s.w = gv.w * rsqrtf(vv.w + BN_EPS); t.w = bv.w - mv.w * s.w;
#pragma unroll
        for (int r = 0; r < 8; ++r) {
            float4 z;
            z.x = fmaf(fmaxf(acc[r][0], 0.f), s.x, t.x);
            z.y = fmaf(fmaxf(acc[r][1], 0.f), s.y, t.y);
            z.z = fmaf(fmaxf(acc[r][2], 0.f), s.z, t.z);
            z.w = fmaf(fmaxf(acc[r][3], 0.f), s.w, t.w);
            *(float4*)&U[tr * 8 + r][tc * 4] = z;   // reads of U finished at last sync
        }
    }
    __syncthreads();

    // ---- GEMM2 + BN2 + ReLU, store ----
    block_gemm(W2l, b2 + layer * D, U, Wc, tid, tr, tc, acc);
    {
        float4 gv = *(const float4*)(g2  + layer * D + tc * 4);
        float4 bv = *(const float4*)(be2 + layer * D + tc * 4);
        float4 mv = *(const float4*)(m2  + layer * D + tc * 4);
        float4 vv = *(const float4*)(v2  + layer * D + tc * 4);
        float4 s, t;
        s.x = gv.x * rsqrtf(vv.x + BN_EPS); t.x = bv.x - mv.x * s.x;
        s.y = gv.y * rsqrtf(vv.y + BN_EPS); t.y = bv.y - mv.y * s.y;
        s.z = gv.z * rsqrtf(vv.z + BN_EPS); t.z = bv.z - mv.z * s.z;
        s.w = gv.w * rsqrtf(vv.w + BN_EPS); t.w = bv.w - mv.w * s.w;
#pragma unroll
        for (int r = 0; r < 8; ++r) {
            int grow = row0 + tr * 8 + r;
            if (grow < N) {
                float4 o;
                o.x = fmaxf(fmaf(acc[r][0], s.x, t.x), 0.f);
                o.y = fmaxf(fmaf(acc[r][1], s.y, t.y), 0.f);
                o.z = fmaxf(fmaf(acc[r][2], s.z, t.z), 0.f);
                o.w = fmaxf(fmaf(acc[r][3], s.w, t.w), 0.f);
                *(float4*)(hout + (size_t)grow * D + tc * 4) = o;
            }
        }
    }
}

extern "C" void kernel_launch(void* const* d_in, const int* in_sizes, int n_in,
                              void* d_out, int out_size, void* d_ws, size_t ws_size,
                              hipStream_t stream)
{
    const float* x   = (const float*)d_in[0];
    const int*   ei  = (const int*)d_in[1];      // int32! harness converts integer inputs
    const float* W1  = (const float*)d_in[2];
    const float* b1  = (const float*)d_in[3];
    const float* g1  = (const float*)d_in[4];
    const float* be1 = (const float*)d_in[5];
    const float* m1  = (const float*)d_in[6];
    const float* v1  = (const float*)d_in[7];
    const float* W2  = (const float*)d_in[8];
    const float* b2  = (const float*)d_in[9];
    const float* eps = (const float*)d_in[10];
    const float* g2  = (const float*)d_in[11];
    const float* be2 = (const float*)d_in[12];
    const float* m2  = (const float*)d_in[13];
    const float* v2  = (const float*)d_in[14];

    const int N = in_sizes[0] / D;
    const int E = in_sizes[1] / 2;
    const int L = in_sizes[10];

    float* out = (float*)d_out;          // doubles as the h ping buffer (in-place safe)
    float* agg = (float*)d_ws;           // N*D fp32 = 51.2 MB scratch

    const int* src = ei;
    const int* dst = ei + E;

    const int scatter_blocks = (E * 32 + 255) / 256;
    const int mlp_blocks     = (N + BM - 1) / BM;

    const float* hin = x;
    for (int l = 0; l < L; ++l) {
        hipMemsetAsync(agg, 0, (size_t)N * D * sizeof(float), stream);
        gin_scatter<<<scatter_blocks, 256, 0, stream>>>(hin, src, dst, agg, E);
        gin_mlp<<<mlp_blocks, 256, 0, stream>>>(hin, agg,
                                                W1, b1, g1, be1, m1, v1,
                                                W2, b2, g2, be2, m2, v2,
                                                eps, l, N, out);
        hin = out;   // layers 1..L-1 run in place on d_out
    }
}

// Round 3
// 1030.388 us; speedup vs baseline: 5.5702x; 5.5702x over previous
//
#include <hip/hip_runtime.h>

#define D 128
#define BM 64
#define BN_EPS 1e-5f
#define SCAN_TPB 256
#define SCAN_EPT 8
#define SCAN_CHUNK (SCAN_TPB * SCAN_EPT)   // 2048 elements per scan block

// ---------------------------------------------------------------------------
// CSR build: histogram -> exclusive scan (3-pass) -> fill. Runs once per
// launch (~50us); kills all float atomics in the per-layer aggregation.
// ---------------------------------------------------------------------------
__global__ __launch_bounds__(256) void csr_hist(
    const int* __restrict__ dst, int* __restrict__ deg, int E)
{
    int e = blockIdx.x * 256 + threadIdx.x;
    if (e < E) atomicAdd(&deg[dst[e]], 1);
}

// In-place exclusive scan of data[0..n): pass A scans 2048-chunks, writes
// per-chunk totals to blk.
__global__ __launch_bounds__(SCAN_TPB) void scan_pass_a(
    int* __restrict__ data, int* __restrict__ blk, int n)
{
    __shared__ int s[SCAN_TPB];
    int tid  = threadIdx.x;
    int base = blockIdx.x * SCAN_CHUNK + tid * SCAN_EPT;
    int v[SCAN_EPT];
    int sum = 0;
#pragma unroll
    for (int i = 0; i < SCAN_EPT; ++i) {
        v[i] = (base + i < n) ? data[base + i] : 0;
        sum += v[i];
    }
    s[tid] = sum;
    __syncthreads();
#pragma unroll
    for (int off = 1; off < SCAN_TPB; off <<= 1) {
        int t = (tid >= off) ? s[tid - off] : 0;
        __syncthreads();
        s[tid] += t;
        __syncthreads();
    }
    int run = s[tid] - sum;   // exclusive prefix of this thread within chunk
#pragma unroll
    for (int i = 0; i < SCAN_EPT; ++i) {
        if (base + i < n) data[base + i] = run;
        run += v[i];
    }
    if (tid == SCAN_TPB - 1) blk[blockIdx.x] = s[SCAN_TPB - 1];
}

// Pass B: single-block exclusive scan of the chunk totals (n <= 2048).
__global__ __launch_bounds__(SCAN_TPB) void scan_pass_b(
    int* __restrict__ data, int n)
{
    __shared__ int s[SCAN_TPB];
    int tid  = threadIdx.x;
    int base = tid * SCAN_EPT;
    int v[SCAN_EPT];
    int sum = 0;
#pragma unroll
    for (int i = 0; i < SCAN_EPT; ++i) {
        v[i] = (base + i < n) ? data[base + i] : 0;
        sum += v[i];
    }
    s[tid] = sum;
    __syncthreads();
#pragma unroll
    for (int off = 1; off < SCAN_TPB; off <<= 1) {
        int t = (tid >= off) ? s[tid - off] : 0;
        __syncthreads();
        s[tid] += t;
        __syncthreads();
    }
    int run = s[tid] - sum;
#pragma unroll
    for (int i = 0; i < SCAN_EPT; ++i) {
        if (base + i < n) data[base + i] = run;
        run += v[i];
    }
}

// Pass C: add chunk offsets; also set row_ptr[n] = E.
__global__ __launch_bounds__(SCAN_TPB) void scan_pass_c(
    int* __restrict__ data, const int* __restrict__ blk, int n, int E)
{
    int base = blockIdx.x * SCAN_CHUNK + threadIdx.x * SCAN_EPT;
    int add  = blk[blockIdx.x];
#pragma unroll
    for (int i = 0; i < SCAN_EPT; ++i)
        if (base + i < n) data[base + i] += add;
    if (blockIdx.x == 0 && threadIdx.x == 0) data[n] = E;
}

__global__ __launch_bounds__(256) void csr_fill(
    const int* __restrict__ src, const int* __restrict__ dst,
    const int* __restrict__ row_ptr, int* __restrict__ fill_pos,
    int* __restrict__ col, int E)
{
    int e = blockIdx.x * 256 + threadIdx.x;
    if (e < E) {
        int d   = dst[e];
        int pos = atomicAdd(&fill_pos[d], 1);
        col[row_ptr[d] + pos] = src[e];
    }
}

// ---------------------------------------------------------------------------
// Block GEMM helper: acc[8][4] = U[64][128] @ W[128][128] + bias, U staged in
// LDS, W streamed through LDS in K=32 chunks.
// ---------------------------------------------------------------------------
__device__ __forceinline__ void block_gemm(
    const float* __restrict__ Wl, const float* __restrict__ bias,
    float (*U)[D + 4], float (*Wc)[D],
    int tid, int tr, int tc, float acc[8][4])
{
    float4 bv = *(const float4*)(bias + tc * 4);
#pragma unroll
    for (int r = 0; r < 8; ++r) {
        acc[r][0] = bv.x; acc[r][1] = bv.y; acc[r][2] = bv.z; acc[r][3] = bv.w;
    }
#pragma unroll 1
    for (int kb = 0; kb < 4; ++kb) {
#pragma unroll
        for (int i = 0; i < 4; ++i) {
            int f4 = tid + 256 * i;
            int kr = f4 >> 5;
            int c  = (f4 & 31) << 2;
            *(float4*)&Wc[kr][c] = *(const float4*)(Wl + (size_t)(kb * 32 + kr) * D + c);
        }
        __syncthreads();
#pragma unroll
        for (int k4 = 0; k4 < 8; ++k4) {
            float4 wv0 = *(const float4*)&Wc[k4 * 4 + 0][tc * 4];
            float4 wv1 = *(const float4*)&Wc[k4 * 4 + 1][tc * 4];
            float4 wv2 = *(const float4*)&Wc[k4 * 4 + 2][tc * 4];
            float4 wv3 = *(const float4*)&Wc[k4 * 4 + 3][tc * 4];
#pragma unroll
            for (int r = 0; r < 8; ++r) {
                float4 uv = *(const float4*)&U[tr * 8 + r][kb * 32 + k4 * 4];
                acc[r][0] = fmaf(uv.x, wv0.x, fmaf(uv.y, wv1.x, fmaf(uv.z, wv2.x, fmaf(uv.w, wv3.x, acc[r][0]))));
                acc[r][1] = fmaf(uv.x, wv0.y, fmaf(uv.y, wv1.y, fmaf(uv.z, wv2.y, fmaf(uv.w, wv3.y, acc[r][1]))));
                acc[r][2] = fmaf(uv.x, wv0.z, fmaf(uv.y, wv1.z, fmaf(uv.z, wv2.z, fmaf(uv.w, wv3.z, acc[r][2]))));
                acc[r][3] = fmaf(uv.x, wv0.w, fmaf(uv.y, wv1.w, fmaf(uv.z, wv2.w, fmaf(uv.w, wv3.w, acc[r][3]))));
            }
        }
        __syncthreads();
    }
}

// ---------------------------------------------------------------------------
// Fused per-layer: gather (CSR) + (1+eps)*h -> U in LDS; MLP both GEMMs;
// store h'. hin != hout (ping-pong) because gather reads other blocks' rows.
// Gather: half-wave (32 lanes) per row, float4/lane = one 512B row read;
// 2-way unrolled j-loop for load ILP.
// ---------------------------------------------------------------------------
__global__ __launch_bounds__(256) void gin_mlp(
    const float* __restrict__ hin,
    const int* __restrict__ row_ptr, const int* __restrict__ col,
    const float* __restrict__ W1, const float* __restrict__ b1,
    const float* __restrict__ g1, const float* __restrict__ be1,
    const float* __restrict__ m1, const float* __restrict__ v1,
    const float* __restrict__ W2, const float* __restrict__ b2,
    const float* __restrict__ g2, const float* __restrict__ be2,
    const float* __restrict__ m2, const float* __restrict__ v2,
    const float* __restrict__ eps, int layer, int N,
    float* __restrict__ hout)
{
    __shared__ float U[BM][D + 4];   // 33.8 KB
    __shared__ float Wc[32][D];      // 16 KB

    const int tid  = threadIdx.x;
    const int tc   = tid & 31;
    const int tr   = tid >> 5;
    const int row0 = blockIdx.x * BM;

    const float epsv = 1.0f + eps[layer];
    const float* W1l = W1 + (size_t)layer * D * D;
    const float* W2l = W2 + (size_t)layer * D * D;

    // ---- fused gather: U[r] = (1+eps)*h[row] + sum_{j} h[col[j]] ----
    {
        const int half = tid >> 5;       // 0..7 half-wave id
        const int c4   = (tid & 31) << 2;
#pragma unroll 1
        for (int rr = half; rr < BM; rr += 8) {
            int grow = row0 + rr;
            float4 a0 = make_float4(0.f, 0.f, 0.f, 0.f);
            float4 a1 = make_float4(0.f, 0.f, 0.f, 0.f);
            if (grow < N) {
                float4 hv = *(const float4*)(hin + (size_t)grow * D + c4);
                a0.x = epsv * hv.x; a0.y = epsv * hv.y;
                a0.z = epsv * hv.z; a0.w = epsv * hv.w;
                int beg = row_ptr[grow];
                int end = row_ptr[grow + 1];
                int j = beg;
                for (; j + 2 <= end; j += 2) {
                    int s0 = col[j];
                    int s1 = col[j + 1];
                    float4 v0 = *(const float4*)(hin + (size_t)s0 * D + c4);
                    float4 v1 = *(const float4*)(hin + (size_t)s1 * D + c4);
                    a0.x += v0.x; a0.y += v0.y; a0.z += v0.z; a0.w += v0.w;
                    a1.x += v1.x; a1.y += v1.y; a1.z += v1.z; a1.w += v1.w;
                }
                if (j < end) {
                    int s0 = col[j];
                    float4 v0 = *(const float4*)(hin + (size_t)s0 * D + c4);
                    a0.x += v0.x; a0.y += v0.y; a0.z += v0.z; a0.w += v0.w;
                }
            }
            float4 r;
            r.x = a0.x + a1.x; r.y = a0.y + a1.y;
            r.z = a0.z + a1.z; r.w = a0.w + a1.w;
            *(float4*)&U[rr][c4] = r;
        }
    }
    __syncthreads();

    float acc[8][4];

    // ---- GEMM1 + ReLU + BN1 back into U ----
    block_gemm(W1l, b1 + layer * D, U, Wc, tid, tr, tc, acc);
    {
        float4 gv = *(const float4*)(g1  + layer * D + tc * 4);
        float4 bv = *(const float4*)(be1 + layer * D + tc * 4);
        float4 mv = *(const float4*)(m1  + layer * D + tc * 4);
        float4 vv = *(const float4*)(v1  + layer * D + tc * 4);
        float4 s, t;
        s.x = gv.x * rsqrtf(vv.x + BN_EPS); t.x = bv.x - mv.x * s.x;
        s.y = gv.y * rsqrtf(vv.y + BN_EPS); t.y = bv.y - mv.y * s.y;
        s.z = gv.z * rsqrtf(vv.z + BN_EPS); t.z = bv.z - mv.z * s.z;
        s.w = gv.w * rsqrtf(vv.w + BN_EPS); t.w = bv.w - mv.w * s.w;
#pragma unroll
        for (int r = 0; r < 8; ++r) {
            float4 z;
            z.x = fmaf(fmaxf(acc[r][0], 0.f), s.x, t.x);
            z.y = fmaf(fmaxf(acc[r][1], 0.f), s.y, t.y);
            z.z = fmaf(fmaxf(acc[r][2], 0.f), s.z, t.z);
            z.w = fmaf(fmaxf(acc[r][3], 0.f), s.w, t.w);
            *(float4*)&U[tr * 8 + r][tc * 4] = z;
        }
    }
    __syncthreads();

    // ---- GEMM2 + BN2 + ReLU, store ----
    block_gemm(W2l, b2 + layer * D, U, Wc, tid, tr, tc, acc);
    {
        float4 gv = *(const float4*)(g2  + layer * D + tc * 4);
        float4 bv = *(const float4*)(be2 + layer * D + tc * 4);
        float4 mv = *(const float4*)(m2  + layer * D + tc * 4);
        float4 vv = *(const float4*)(v2  + layer * D + tc * 4);
        float4 s, t;
        s.x = gv.x * rsqrtf(vv.x + BN_EPS); t.x = bv.x - mv.x * s.x;
        s.y = gv.y * rsqrtf(vv.y + BN_EPS); t.y = bv.y - mv.y * s.y;
        s.z = gv.z * rsqrtf(vv.z + BN_EPS); t.z = bv.z - mv.z * s.z;
        s.w = gv.w * rsqrtf(vv.w + BN_EPS); t.w = bv.w - mv.w * s.w;
#pragma unroll
        for (int r = 0; r < 8; ++r) {
            int grow = row0 + tr * 8 + r;
            if (grow < N) {
                float4 o;
                o.x = fmaxf(fmaf(acc[r][0], s.x, t.x), 0.f);
                o.y = fmaxf(fmaf(acc[r][1], s.y, t.y), 0.f);
                o.z = fmaxf(fmaf(acc[r][2], s.z, t.z), 0.f);
                o.w = fmaxf(fmaf(acc[r][3], s.w, t.w), 0.f);
                *(float4*)(hout + (size_t)grow * D + tc * 4) = o;
            }
        }
    }
}

extern "C" void kernel_launch(void* const* d_in, const int* in_sizes, int n_in,
                              void* d_out, int out_size, void* d_ws, size_t ws_size,
                              hipStream_t stream)
{
    const float* x   = (const float*)d_in[0];
    const int*   ei  = (const int*)d_in[1];      // int32 on device
    const float* W1  = (const float*)d_in[2];
    const float* b1  = (const float*)d_in[3];
    const float* g1  = (const float*)d_in[4];
    const float* be1 = (const float*)d_in[5];
    const float* m1  = (const float*)d_in[6];
    const float* v1  = (const float*)d_in[7];
    const float* W2  = (const float*)d_in[8];
    const float* b2  = (const float*)d_in[9];
    const float* eps = (const float*)d_in[10];
    const float* g2  = (const float*)d_in[11];
    const float* be2 = (const float*)d_in[12];
    const float* m2  = (const float*)d_in[13];
    const float* v2  = (const float*)d_in[14];

    const int N = in_sizes[0] / D;
    const int E = in_sizes[1] / 2;
    const int L = in_sizes[10];

    float* out = (float*)d_out;

    // ws layout: hbuf | row_ptr | blk | fill_pos | col
    float* hbuf     = (float*)d_ws;
    int*   row_ptr  = (int*)(hbuf + (size_t)N * D);
    int*   blk      = row_ptr + (N + 1);
    int*   fill_pos = blk + 2048;
    int*   col      = fill_pos + N;

    const int* src = ei;
    const int* dst = ei + E;

    const int NB = (N + SCAN_CHUNK - 1) / SCAN_CHUNK;

    // ---- CSR build (once per launch) ----
    hipMemsetAsync(row_ptr, 0, (size_t)(N + 1 + 2048 + N) * sizeof(int), stream);
    csr_hist<<<(E + 255) / 256, 256, 0, stream>>>(dst, row_ptr, E);
    scan_pass_a<<<NB, SCAN_TPB, 0, stream>>>(row_ptr, blk, N);
    scan_pass_b<<<1, SCAN_TPB, 0, stream>>>(blk, NB);
    scan_pass_c<<<NB, SCAN_TPB, 0, stream>>>(row_ptr, blk, N, E);
    csr_fill<<<(E + 255) / 256, 256, 0, stream>>>(src, dst, row_ptr, fill_pos, col, E);

    // ---- layers: ping-pong h between d_out and hbuf, final lands in d_out ----
    const int mlp_blocks = (N + BM - 1) / BM;
    const float* hin = x;
    for (int l = 0; l < L; ++l) {
        float* hout = (((L - 1 - l) & 1) == 0) ? out : hbuf;
        gin_mlp<<<mlp_blocks, 256, 0, stream>>>(hin, row_ptr, col,
                                                W1, b1, g1, be1, m1, v1,
                                                W2, b2, g2, be2, m2, v2,
                                                eps, l, N, hout);
        hin = hout;
    }
}

// Round 4
// 961.192 us; speedup vs baseline: 5.9712x; 1.0720x over previous
//
#include <hip/hip_runtime.h>

#define D 128
#define BM 64
#define BN_EPS 1e-5f
#define SCAN_TPB 256
#define SCAN_EPT 8
#define SCAN_CHUNK (SCAN_TPB * SCAN_EPT)   // 2048 elements per scan block

// ---------------------------------------------------------------------------
// CSR build: histogram -> exclusive scan (3-pass) -> fill. ~30-50us once per
// launch.
// ---------------------------------------------------------------------------
__global__ __launch_bounds__(256) void csr_hist(
    const int* __restrict__ dst, int* __restrict__ deg, int E)
{
    int e = blockIdx.x * 256 + threadIdx.x;
    if (e < E) atomicAdd(&deg[dst[e]], 1);
}

__global__ __launch_bounds__(SCAN_TPB) void scan_pass_a(
    int* __restrict__ data, int* __restrict__ blk, int n)
{
    __shared__ int s[SCAN_TPB];
    int tid  = threadIdx.x;
    int base = blockIdx.x * SCAN_CHUNK + tid * SCAN_EPT;
    int v[SCAN_EPT];
    int sum = 0;
#pragma unroll
    for (int i = 0; i < SCAN_EPT; ++i) {
        v[i] = (base + i < n) ? data[base + i] : 0;
        sum += v[i];
    }
    s[tid] = sum;
    __syncthreads();
#pragma unroll
    for (int off = 1; off < SCAN_TPB; off <<= 1) {
        int t = (tid >= off) ? s[tid - off] : 0;
        __syncthreads();
        s[tid] += t;
        __syncthreads();
    }
    int run = s[tid] - sum;
#pragma unroll
    for (int i = 0; i < SCAN_EPT; ++i) {
        if (base + i < n) data[base + i] = run;
        run += v[i];
    }
    if (tid == SCAN_TPB - 1) blk[blockIdx.x] = s[SCAN_TPB - 1];
}

__global__ __launch_bounds__(SCAN_TPB) void scan_pass_b(
    int* __restrict__ data, int n)
{
    __shared__ int s[SCAN_TPB];
    int tid  = threadIdx.x;
    int base = tid * SCAN_EPT;
    int v[SCAN_EPT];
    int sum = 0;
#pragma unroll
    for (int i = 0; i < SCAN_EPT; ++i) {
        v[i] = (base + i < n) ? data[base + i] : 0;
        sum += v[i];
    }
    s[tid] = sum;
    __syncthreads();
#pragma unroll
    for (int off = 1; off < SCAN_TPB; off <<= 1) {
        int t = (tid >= off) ? s[tid - off] : 0;
        __syncthreads();
        s[tid] += t;
        __syncthreads();
    }
    int run = s[tid] - sum;
#pragma unroll
    for (int i = 0; i < SCAN_EPT; ++i) {
        if (base + i < n) data[base + i] = run;
        run += v[i];
    }
}

__global__ __launch_bounds__(SCAN_TPB) void scan_pass_c(
    int* __restrict__ data, const int* __restrict__ blk, int n, int E)
{
    int base = blockIdx.x * SCAN_CHUNK + threadIdx.x * SCAN_EPT;
    int add  = blk[blockIdx.x];
#pragma unroll
    for (int i = 0; i < SCAN_EPT; ++i)
        if (base + i < n) data[base + i] += add;
    if (blockIdx.x == 0 && threadIdx.x == 0) data[n] = E;
}

__global__ __launch_bounds__(256) void csr_fill(
    const int* __restrict__ src, const int* __restrict__ dst,
    const int* __restrict__ row_ptr, int* __restrict__ fill_pos,
    int* __restrict__ col, int E)
{
    int e = blockIdx.x * 256 + threadIdx.x;
    if (e < E) {
        int d   = dst[e];
        int pos = atomicAdd(&fill_pos[d], 1);
        col[row_ptr[d] + pos] = src[e];
    }
}

// ---------------------------------------------------------------------------
// Gather: U[row] = (1+eps)*h[row] + sum_nbr h[col].  One row per HALF-WAVE
// (32 lanes x float4 = one 512B row read). No LDS -> high occupancy. Col
// indices loaded once coalesced and broadcast with shfl(width 32); neighbor
// rows fetched 8-deep with clamp+weight predication (no divergent remainder).
// ---------------------------------------------------------------------------
__global__ __launch_bounds__(256) void gin_gather(
    const float* __restrict__ h,
    const int* __restrict__ row_ptr, const int* __restrict__ col,
    const float* __restrict__ eps, int layer,
    float* __restrict__ U, int N)
{
    int gid  = blockIdx.x * 256 + threadIdx.x;
    int row  = gid >> 5;
    int lane = threadIdx.x & 31;
    int c4   = lane << 2;
    if (row >= N) return;

    const float epsv = 1.0f + eps[layer];
    float4 acc;
    {
        float4 hv = *(const float4*)(h + (size_t)row * D + c4);
        acc.x = epsv * hv.x; acc.y = epsv * hv.y;
        acc.z = epsv * hv.z; acc.w = epsv * hv.w;
    }

    int j   = row_ptr[row];
    int end = row_ptr[row + 1];
    while (j < end) {
        int cnt = min(end - j, 32);
        int ci  = col[j + min(lane, cnt - 1)];   // coalesced, clamped tail
#pragma unroll 1
        for (int k = 0; k < cnt; k += 8) {
            int k0 = min(k + 0, cnt - 1), k1 = min(k + 1, cnt - 1);
            int k2 = min(k + 2, cnt - 1), k3 = min(k + 3, cnt - 1);
            int k4 = min(k + 4, cnt - 1), k5 = min(k + 5, cnt - 1);
            int k6 = min(k + 6, cnt - 1), k7 = min(k + 7, cnt - 1);
            int s0 = __shfl(ci, k0, 32), s1 = __shfl(ci, k1, 32);
            int s2 = __shfl(ci, k2, 32), s3 = __shfl(ci, k3, 32);
            int s4 = __shfl(ci, k4, 32), s5 = __shfl(ci, k5, 32);
            int s6 = __shfl(ci, k6, 32), s7 = __shfl(ci, k7, 32);
            float w1 = (k + 1 < cnt) ? 1.f : 0.f;
            float w2 = (k + 2 < cnt) ? 1.f : 0.f;
            float w3 = (k + 3 < cnt) ? 1.f : 0.f;
            float w4 = (k + 4 < cnt) ? 1.f : 0.f;
            float w5 = (k + 5 < cnt) ? 1.f : 0.f;
            float w6 = (k + 6 < cnt) ? 1.f : 0.f;
            float w7 = (k + 7 < cnt) ? 1.f : 0.f;
            float4 v0 = *(const float4*)(h + (size_t)s0 * D + c4);
            float4 v1 = *(const float4*)(h + (size_t)s1 * D + c4);
            float4 v2 = *(const float4*)(h + (size_t)s2 * D + c4);
            float4 v3 = *(const float4*)(h + (size_t)s3 * D + c4);
            float4 v4 = *(const float4*)(h + (size_t)s4 * D + c4);
            float4 v5 = *(const float4*)(h + (size_t)s5 * D + c4);
            float4 v6 = *(const float4*)(h + (size_t)s6 * D + c4);
            float4 v7 = *(const float4*)(h + (size_t)s7 * D + c4);
            acc.x += v0.x; acc.y += v0.y; acc.z += v0.z; acc.w += v0.w;
            acc.x = fmaf(w1, v1.x, acc.x); acc.y = fmaf(w1, v1.y, acc.y);
            acc.z = fmaf(w1, v1.z, acc.z); acc.w = fmaf(w1, v1.w, acc.w);
            acc.x = fmaf(w2, v2.x, acc.x); acc.y = fmaf(w2, v2.y, acc.y);
            acc.z = fmaf(w2, v2.z, acc.z); acc.w = fmaf(w2, v2.w, acc.w);
            acc.x = fmaf(w3, v3.x, acc.x); acc.y = fmaf(w3, v3.y, acc.y);
            acc.z = fmaf(w3, v3.z, acc.z); acc.w = fmaf(w3, v3.w, acc.w);
            acc.x = fmaf(w4, v4.x, acc.x); acc.y = fmaf(w4, v4.y, acc.y);
            acc.z = fmaf(w4, v4.z, acc.z); acc.w = fmaf(w4, v4.w, acc.w);
            acc.x = fmaf(w5, v5.x, acc.x); acc.y = fmaf(w5, v5.y, acc.y);
            acc.z = fmaf(w5, v5.z, acc.z); acc.w = fmaf(w5, v5.w, acc.w);
            acc.x = fmaf(w6, v6.x, acc.x); acc.y = fmaf(w6, v6.y, acc.y);
            acc.z = fmaf(w6, v6.z, acc.z); acc.w = fmaf(w6, v6.w, acc.w);
            acc.x = fmaf(w7, v7.x, acc.x); acc.y = fmaf(w7, v7.y, acc.y);
            acc.z = fmaf(w7, v7.z, acc.z); acc.w = fmaf(w7, v7.w, acc.w);
        }
        j += cnt;
    }

    *(float4*)(U + (size_t)row * D + c4) = acc;
}

// ---------------------------------------------------------------------------
// Block GEMM helper: acc[8][4] = U[64][128] @ W[128][128] + bias.
// ---------------------------------------------------------------------------
__device__ __forceinline__ void block_gemm(
    const float* __restrict__ Wl, const float* __restrict__ bias,
    float (*U)[D + 4], float (*Wc)[D],
    int tid, int tr, int tc, float acc[8][4])
{
    float4 bv = *(const float4*)(bias + tc * 4);
#pragma unroll
    for (int r = 0; r < 8; ++r) {
        acc[r][0] = bv.x; acc[r][1] = bv.y; acc[r][2] = bv.z; acc[r][3] = bv.w;
    }
#pragma unroll 1
    for (int kb = 0; kb < 4; ++kb) {
#pragma unroll
        for (int i = 0; i < 4; ++i) {
            int f4 = tid + 256 * i;
            int kr = f4 >> 5;
            int c  = (f4 & 31) << 2;
            *(float4*)&Wc[kr][c] = *(const float4*)(Wl + (size_t)(kb * 32 + kr) * D + c);
        }
        __syncthreads();
#pragma unroll
        for (int k4 = 0; k4 < 8; ++k4) {
            float4 wv0 = *(const float4*)&Wc[k4 * 4 + 0][tc * 4];
            float4 wv1 = *(const float4*)&Wc[k4 * 4 + 1][tc * 4];
            float4 wv2 = *(const float4*)&Wc[k4 * 4 + 2][tc * 4];
            float4 wv3 = *(const float4*)&Wc[k4 * 4 + 3][tc * 4];
#pragma unroll
            for (int r = 0; r < 8; ++r) {
                float4 uv = *(const float4*)&U[tr * 8 + r][kb * 32 + k4 * 4];
                acc[r][0] = fmaf(uv.x, wv0.x, fmaf(uv.y, wv1.x, fmaf(uv.z, wv2.x, fmaf(uv.w, wv3.x, acc[r][0]))));
                acc[r][1] = fmaf(uv.x, wv0.y, fmaf(uv.y, wv1.y, fmaf(uv.z, wv2.y, fmaf(uv.w, wv3.y, acc[r][1]))));
                acc[r][2] = fmaf(uv.x, wv0.z, fmaf(uv.y, wv1.z, fmaf(uv.z, wv2.z, fmaf(uv.w, wv3.z, acc[r][2]))));
                acc[r][3] = fmaf(uv.x, wv0.w, fmaf(uv.y, wv1.w, fmaf(uv.z, wv2.w, fmaf(uv.w, wv3.w, acc[r][3]))));
            }
        }
        __syncthreads();
    }
}

// ---------------------------------------------------------------------------
// MLP: reads pre-aggregated U, runs both GEMMs with fused BN/ReLU, stores h'.
// ---------------------------------------------------------------------------
__global__ __launch_bounds__(256) void gin_mlp(
    const float* __restrict__ Uin,
    const float* __restrict__ W1, const float* __restrict__ b1,
    const float* __restrict__ g1, const float* __restrict__ be1,
    const float* __restrict__ m1, const float* __restrict__ v1,
    const float* __restrict__ W2, const float* __restrict__ b2,
    const float* __restrict__ g2, const float* __restrict__ be2,
    const float* __restrict__ m2, const float* __restrict__ v2,
    int layer, int N, float* __restrict__ hout)
{
    __shared__ float U[BM][D + 4];   // 33.8 KB
    __shared__ float Wc[32][D];      // 16 KB

    const int tid  = threadIdx.x;
    const int tc   = tid & 31;
    const int tr   = tid >> 5;
    const int row0 = blockIdx.x * BM;

    const float* W1l = W1 + (size_t)layer * D * D;
    const float* W2l = W2 + (size_t)layer * D * D;

    // ---- stage U tile from global (coalesced) ----
#pragma unroll
    for (int i = 0; i < 8; ++i) {
        int f4 = tid + 256 * i;
        int r  = f4 >> 5;
        int c  = (f4 & 31) << 2;
        int grow = row0 + r;
        float4 u = make_float4(0.f, 0.f, 0.f, 0.f);
        if (grow < N) u = *(const float4*)(Uin + (size_t)grow * D + c);
        *(float4*)&U[r][c] = u;
    }
    __syncthreads();

    float acc[8][4];

    // ---- GEMM1 + ReLU + BN1 back into U ----
    block_gemm(W1l, b1 + layer * D, U, Wc, tid, tr, tc, acc);
    {
        float4 gv = *(const float4*)(g1  + layer * D + tc * 4);
        float4 bv = *(const float4*)(be1 + layer * D + tc * 4);
        float4 mv = *(const float4*)(m1  + layer * D + tc * 4);
        float4 vv = *(const float4*)(v1  + layer * D + tc * 4);
        float4 s, t;
        s.x = gv.x * rsqrtf(vv.x + BN_EPS); t.x = bv.x - mv.x * s.x;
        s.y = gv.y * rsqrtf(vv.y + BN_EPS); t.y = bv.y - mv.y * s.y;
        s.z = gv.z * rsqrtf(vv.z + BN_EPS); t.z = bv.z - mv.z * s.z;
        s.w = gv.w * rsqrtf(vv.w + BN_EPS); t.w = bv.w - mv.w * s.w;
#pragma unroll
        for (int r = 0; r < 8; ++r) {
            float4 z;
            z.x = fmaf(fmaxf(acc[r][0], 0.f), s.x, t.x);
            z.y = fmaf(fmaxf(acc[r][1], 0.f), s.y, t.y);
            z.z = fmaf(fmaxf(acc[r][2], 0.f), s.z, t.z);
            z.w = fmaf(fmaxf(acc[r][3], 0.f), s.w, t.w);
            *(float4*)&U[tr * 8 + r][tc * 4] = z;
        }
    }
    __syncthreads();

    // ---- GEMM2 + BN2 + ReLU, store ----
    block_gemm(W2l, b2 + layer * D, U, Wc, tid, tr, tc, acc);
    {
        float4 gv = *(const float4*)(g2  + layer * D + tc * 4);
        float4 bv = *(const float4*)(be2 + layer * D + tc * 4);
        float4 mv = *(const float4*)(m2  + layer * D + tc * 4);
        float4 vv = *(const float4*)(v2  + layer * D + tc * 4);
        float4 s, t;
        s.x = gv.x * rsqrtf(vv.x + BN_EPS); t.x = bv.x - mv.x * s.x;
        s.y = gv.y * rsqrtf(vv.y + BN_EPS); t.y = bv.y - mv.y * s.y;
        s.z = gv.z * rsqrtf(vv.z + BN_EPS); t.z = bv.z - mv.z * s.z;
        s.w = gv.w * rsqrtf(vv.w + BN_EPS); t.w = bv.w - mv.w * s.w;
#pragma unroll
        for (int r = 0; r < 8; ++r) {
            int grow = row0 + tr * 8 + r;
            if (grow < N) {
                float4 o;
                o.x = fmaxf(fmaf(acc[r][0], s.x, t.x), 0.f);
                o.y = fmaxf(fmaf(acc[r][1], s.y, t.y), 0.f);
                o.z = fmaxf(fmaf(acc[r][2], s.z, t.z), 0.f);
                o.w = fmaxf(fmaf(acc[r][3], s.w, t.w), 0.f);
                *(float4*)(hout + (size_t)grow * D + tc * 4) = o;
            }
        }
    }
}

extern "C" void kernel_launch(void* const* d_in, const int* in_sizes, int n_in,
                              void* d_out, int out_size, void* d_ws, size_t ws_size,
                              hipStream_t stream)
{
    const float* x   = (const float*)d_in[0];
    const int*   ei  = (const int*)d_in[1];      // int32 on device
    const float* W1  = (const float*)d_in[2];
    const float* b1  = (const float*)d_in[3];
    const float* g1  = (const float*)d_in[4];
    const float* be1 = (const float*)d_in[5];
    const float* m1  = (const float*)d_in[6];
    const float* v1  = (const float*)d_in[7];
    const float* W2  = (const float*)d_in[8];
    const float* b2  = (const float*)d_in[9];
    const float* eps = (const float*)d_in[10];
    const float* g2  = (const float*)d_in[11];
    const float* be2 = (const float*)d_in[12];
    const float* m2  = (const float*)d_in[13];
    const float* v2  = (const float*)d_in[14];

    const int N = in_sizes[0] / D;
    const int E = in_sizes[1] / 2;
    const int L = in_sizes[10];

    float* out = (float*)d_out;   // h lives here from layer 0 onward

    // ws layout: U | row_ptr | blk | fill_pos | col   (~54.4 MB)
    float* U        = (float*)d_ws;
    int*   row_ptr  = (int*)(U + (size_t)N * D);
    int*   blk      = row_ptr + (N + 1);
    int*   fill_pos = blk + 2048;
    int*   col      = fill_pos + N;

    const int* src = ei;
    const int* dst = ei + E;

    const int NB = (N + SCAN_CHUNK - 1) / SCAN_CHUNK;

    // ---- CSR build (once per launch) ----
    hipMemsetAsync(row_ptr, 0, (size_t)(N + 1 + 2048 + N) * sizeof(int), stream);
    csr_hist<<<(E + 255) / 256, 256, 0, stream>>>(dst, row_ptr, E);
    scan_pass_a<<<NB, SCAN_TPB, 0, stream>>>(row_ptr, blk, N);
    scan_pass_b<<<1, SCAN_TPB, 0, stream>>>(blk, NB);
    scan_pass_c<<<NB, SCAN_TPB, 0, stream>>>(row_ptr, blk, N, E);
    csr_fill<<<(E + 255) / 256, 256, 0, stream>>>(src, dst, row_ptr, fill_pos, col, E);

    // ---- layers: gather(h -> U), mlp(U -> h in d_out) ----
    const int gather_blocks = (N + 7) / 8;       // one row per half-wave
    const int mlp_blocks    = (N + BM - 1) / BM;
    const float* hin = x;
    for (int l = 0; l < L; ++l) {
        gin_gather<<<gather_blocks, 256, 0, stream>>>(hin, row_ptr, col, eps, l, U, N);
        gin_mlp<<<mlp_blocks, 256, 0, stream>>>(U,
                                                W1, b1, g1, be1, m1, v1,
                                                W2, b2, g2, be2, m2, v2,
                                                l, N, out);
        hin = out;
    }
}

// Round 5
// 682.109 us; speedup vs baseline: 8.4143x; 1.4091x over previous
//
#include <hip/hip_runtime.h>

#define D 128
#define BN_EPS 1e-5f
#define SCAN_TPB 256
#define SCAN_EPT 8
#define SCAN_CHUNK (SCAN_TPB * SCAN_EPT)

typedef __attribute__((ext_vector_type(8))) short bf16x8;
typedef __attribute__((ext_vector_type(4))) float f32x4;

__device__ __forceinline__ unsigned short f2bf_rn(float f) {
    unsigned u = __float_as_uint(f);
    u += 0x7FFFu + ((u >> 16) & 1u);
    return (unsigned short)(u >> 16);
}
// pack fp32 -> (bf16_hi << 16) | bf16_lo(residual)
__device__ __forceinline__ unsigned packsplit(float x) {
    unsigned short h = f2bf_rn(x);
    float r = x - __uint_as_float((unsigned)h << 16);
    return ((unsigned)h << 16) | (unsigned)f2bf_rn(r);
}

// ---------------------------------------------------------------------------
// CSR build: histogram -> exclusive scan -> fill (once per launch).
// ---------------------------------------------------------------------------
__global__ __launch_bounds__(256) void csr_hist(
    const int* __restrict__ dst, int* __restrict__ deg, int E)
{
    int e = blockIdx.x * 256 + threadIdx.x;
    if (e < E) atomicAdd(&deg[dst[e]], 1);
}

__global__ __launch_bounds__(SCAN_TPB) void scan_pass_a(
    int* __restrict__ data, int* __restrict__ blk, int n)
{
    __shared__ int s[SCAN_TPB];
    int tid  = threadIdx.x;
    int base = blockIdx.x * SCAN_CHUNK + tid * SCAN_EPT;
    int v[SCAN_EPT];
    int sum = 0;
#pragma unroll
    for (int i = 0; i < SCAN_EPT; ++i) {
        v[i] = (base + i < n) ? data[base + i] : 0;
        sum += v[i];
    }
    s[tid] = sum;
    __syncthreads();
#pragma unroll
    for (int off = 1; off < SCAN_TPB; off <<= 1) {
        int t = (tid >= off) ? s[tid - off] : 0;
        __syncthreads();
        s[tid] += t;
        __syncthreads();
    }
    int run = s[tid] - sum;
#pragma unroll
    for (int i = 0; i < SCAN_EPT; ++i) {
        if (base + i < n) data[base + i] = run;
        run += v[i];
    }
    if (tid == SCAN_TPB - 1) blk[blockIdx.x] = s[SCAN_TPB - 1];
}

__global__ __launch_bounds__(SCAN_TPB) void scan_pass_b(
    int* __restrict__ data, int n)
{
    __shared__ int s[SCAN_TPB];
    int tid  = threadIdx.x;
    int base = tid * SCAN_EPT;
    int v[SCAN_EPT];
    int sum = 0;
#pragma unroll
    for (int i = 0; i < SCAN_EPT; ++i) {
        v[i] = (base + i < n) ? data[base + i] : 0;
        sum += v[i];
    }
    s[tid] = sum;
    __syncthreads();
#pragma unroll
    for (int off = 1; off < SCAN_TPB; off <<= 1) {
        int t = (tid >= off) ? s[tid - off] : 0;
        __syncthreads();
        s[tid] += t;
        __syncthreads();
    }
    int run = s[tid] - sum;
#pragma unroll
    for (int i = 0; i < SCAN_EPT; ++i) {
        if (base + i < n) data[base + i] = run;
        run += v[i];
    }
}

__global__ __launch_bounds__(SCAN_TPB) void scan_pass_c(
    int* __restrict__ data, const int* __restrict__ blk, int n, int E)
{
    int base = blockIdx.x * SCAN_CHUNK + threadIdx.x * SCAN_EPT;
    int add  = blk[blockIdx.x];
#pragma unroll
    for (int i = 0; i < SCAN_EPT; ++i)
        if (base + i < n) data[base + i] += add;
    if (blockIdx.x == 0 && threadIdx.x == 0) data[n] = E;
}

__global__ __launch_bounds__(256) void csr_fill(
    const int* __restrict__ src, const int* __restrict__ dst,
    const int* __restrict__ row_ptr, int* __restrict__ fill_pos,
    int* __restrict__ col, int E)
{
    int e = blockIdx.x * 256 + threadIdx.x;
    if (e < E) {
        int d   = dst[e];
        int pos = atomicAdd(&fill_pos[d], 1);
        col[row_ptr[d] + pos] = src[e];
    }
}

// ---------------------------------------------------------------------------
// Weight pre-split: fp32 W -> bf16 hi/lo in MFMA B-fragment order, so the MLP
// kernel's B-frag is ONE 16B global load per lane. Layout element index:
// (((g2s)*4 + ks)*8 + nt)*512 + lane*8 + j, where g2s = (layer*2+gemm)*2+split,
// k = ks*32 + (lane>>4)*8 + j, n = nt*16 + (lane&15).
// ---------------------------------------------------------------------------
__global__ __launch_bounds__(256) void w_split(
    const float* __restrict__ W1, const float* __restrict__ W2,
    unsigned short* __restrict__ Wsw, int total)
{
    int t = blockIdx.x * 256 + threadIdx.x;
    if (t >= total) return;                 // total = L*2*4*8*64
    int lane = t & 63;
    int nt   = (t >> 6) & 7;
    int ks   = (t >> 9) & 3;
    int g    = t >> 11;                     // layer*2 + gemm
    int layer = g >> 1, gemm = g & 1;
    const float* W = (gemm ? W2 : W1) + (size_t)layer * D * D;
    int n  = nt * 16 + (lane & 15);
    int kb = ks * 32 + (lane >> 4) * 8;
    union { unsigned short s[8]; uint4 q; } uh, ul;
#pragma unroll
    for (int j = 0; j < 8; ++j) {
        float x = W[(size_t)(kb + j) * D + n];
        unsigned short h = f2bf_rn(x);
        float r = x - __uint_as_float((unsigned)h << 16);
        uh.s[j] = h;
        ul.s[j] = f2bf_rn(r);
    }
    size_t ehi = ((((size_t)g * 2 + 0) * 4 + ks) * 8 + nt) * 512 + (size_t)lane * 8;
    size_t elo = ((((size_t)g * 2 + 1) * 4 + ks) * 8 + nt) * 512 + (size_t)lane * 8;
    *(uint4*)&Wsw[ehi] = uh.q;
    *(uint4*)&Wsw[elo] = ul.q;
}

// ---------------------------------------------------------------------------
// Gather: U[row] = (1+eps)*h[row] + sum_nbr h[col]. One row per half-wave.
// ---------------------------------------------------------------------------
__global__ __launch_bounds__(256) void gin_gather(
    const float* __restrict__ h,
    const int* __restrict__ row_ptr, const int* __restrict__ col,
    const float* __restrict__ eps, int layer,
    float* __restrict__ U, int N)
{
    int gid  = blockIdx.x * 256 + threadIdx.x;
    int row  = gid >> 5;
    int lane = threadIdx.x & 31;
    int c4   = lane << 2;
    if (row >= N) return;

    const float epsv = 1.0f + eps[layer];
    float4 acc;
    {
        float4 hv = *(const float4*)(h + (size_t)row * D + c4);
        acc.x = epsv * hv.x; acc.y = epsv * hv.y;
        acc.z = epsv * hv.z; acc.w = epsv * hv.w;
    }

    int j   = row_ptr[row];
    int end = row_ptr[row + 1];
    while (j < end) {
        int cnt = min(end - j, 32);
        int ci  = col[j + min(lane, cnt - 1)];
#pragma unroll 1
        for (int k = 0; k < cnt; k += 8) {
            int k0 = min(k + 0, cnt - 1), k1 = min(k + 1, cnt - 1);
            int k2 = min(k + 2, cnt - 1), k3 = min(k + 3, cnt - 1);
            int k4 = min(k + 4, cnt - 1), k5 = min(k + 5, cnt - 1);
            int k6 = min(k + 6, cnt - 1), k7 = min(k + 7, cnt - 1);
            int s0 = __shfl(ci, k0, 32), s1 = __shfl(ci, k1, 32);
            int s2 = __shfl(ci, k2, 32), s3 = __shfl(ci, k3, 32);
            int s4 = __shfl(ci, k4, 32), s5 = __shfl(ci, k5, 32);
            int s6 = __shfl(ci, k6, 32), s7 = __shfl(ci, k7, 32);
            float w1 = (k + 1 < cnt) ? 1.f : 0.f;
            float w2 = (k + 2 < cnt) ? 1.f : 0.f;
            float w3 = (k + 3 < cnt) ? 1.f : 0.f;
            float w4 = (k + 4 < cnt) ? 1.f : 0.f;
            float w5 = (k + 5 < cnt) ? 1.f : 0.f;
            float w6 = (k + 6 < cnt) ? 1.f : 0.f;
            float w7 = (k + 7 < cnt) ? 1.f : 0.f;
            float4 v0 = *(const float4*)(h + (size_t)s0 * D + c4);
            float4 v1 = *(const float4*)(h + (size_t)s1 * D + c4);
            float4 v2 = *(const float4*)(h + (size_t)s2 * D + c4);
            float4 v3 = *(const float4*)(h + (size_t)s3 * D + c4);
            float4 v4 = *(const float4*)(h + (size_t)s4 * D + c4);
            float4 v5 = *(const float4*)(h + (size_t)s5 * D + c4);
            float4 v6 = *(const float4*)(h + (size_t)s6 * D + c4);
            float4 v7 = *(const float4*)(h + (size_t)s7 * D + c4);
            acc.x += v0.x; acc.y += v0.y; acc.z += v0.z; acc.w += v0.w;
            acc.x = fmaf(w1, v1.x, acc.x); acc.y = fmaf(w1, v1.y, acc.y);
            acc.z = fmaf(w1, v1.z, acc.z); acc.w = fmaf(w1, v1.w, acc.w);
            acc.x = fmaf(w2, v2.x, acc.x); acc.y = fmaf(w2, v2.y, acc.y);
            acc.z = fmaf(w2, v2.z, acc.z); acc.w = fmaf(w2, v2.w, acc.w);
            acc.x = fmaf(w3, v3.x, acc.x); acc.y = fmaf(w3, v3.y, acc.y);
            acc.z = fmaf(w3, v3.z, acc.z); acc.w = fmaf(w3, v3.w, acc.w);
            acc.x = fmaf(w4, v4.x, acc.x); acc.y = fmaf(w4, v4.y, acc.y);
            acc.z = fmaf(w4, v4.z, acc.z); acc.w = fmaf(w4, v4.w, acc.w);
            acc.x = fmaf(w5, v5.x, acc.x); acc.y = fmaf(w5, v5.y, acc.y);
            acc.z = fmaf(w5, v5.z, acc.z); acc.w = fmaf(w5, v5.w, acc.w);
            acc.x = fmaf(w6, v6.x, acc.x); acc.y = fmaf(w6, v6.y, acc.y);
            acc.z = fmaf(w6, v6.z, acc.z); acc.w = fmaf(w6, v6.w, acc.w);
            acc.x = fmaf(w7, v7.x, acc.x); acc.y = fmaf(w7, v7.y, acc.y);
            acc.z = fmaf(w7, v7.z, acc.z); acc.w = fmaf(w7, v7.w, acc.w);
        }
        j += cnt;
    }

    *(float4*)(U + (size_t)row * D + c4) = acc;
}

// ---------------------------------------------------------------------------
// MFMA MLP. Block = 256 thr = 4 waves; block tile M=64, each wave owns a
// 16-row strip end-to-end (no inter-wave dependencies after staging).
// Up LDS holds activations as packed (bf16_hi | bf16_lo) dwords, row stride
// 132 (16B-aligned, <=2-way bank alias = free). B-frags load pre-swizzled
// bf16 directly from global (L2-resident). 3 MFMAs per site (hi*hi + hi*lo
// + lo*hi) give ~fp32 precision at bf16 rate.
// ---------------------------------------------------------------------------
__device__ __forceinline__ void mfma_gemm16(
    const unsigned (*Up)[132], const unsigned short* __restrict__ Wsw,
    int g2s_hi, const float* __restrict__ bsLDS,
    int m0, int lane, f32x4 acc[8])
{
    const int col16 = lane & 15;
#pragma unroll
    for (int nt = 0; nt < 8; ++nt) {
        float b = bsLDS[nt * 16 + col16];
        acc[nt][0] = b; acc[nt][1] = b; acc[nt][2] = b; acc[nt][3] = b;
    }
    const int arow = m0 + (lane & 15);
#pragma unroll
    for (int ks = 0; ks < 4; ++ks) {
        const int kb = ks * 32 + (lane >> 4) * 8;
        uint4 p0 = *(const uint4*)&Up[arow][kb];
        uint4 p1 = *(const uint4*)&Up[arow][kb + 4];
        unsigned pp[8] = {p0.x, p0.y, p0.z, p0.w, p1.x, p1.y, p1.z, p1.w};
        union { unsigned u[4]; bf16x8 v; } ah, al;
#pragma unroll
        for (int j = 0; j < 4; ++j) {
            ah.u[j] = (pp[2*j] >> 16)      | (pp[2*j+1] & 0xFFFF0000u);
            al.u[j] = (pp[2*j] & 0xFFFFu)  | (pp[2*j+1] << 16);
        }
        const unsigned short* whB =
            Wsw + ((((size_t)g2s_hi)     * 4 + ks) * 8) * 512 + (size_t)lane * 8;
        const unsigned short* wlB =
            Wsw + ((((size_t)g2s_hi + 1) * 4 + ks) * 8) * 512 + (size_t)lane * 8;
#pragma unroll
        for (int nt = 0; nt < 8; ++nt) {
            bf16x8 bh = *(const bf16x8*)(whB + (size_t)nt * 512);
            bf16x8 bl = *(const bf16x8*)(wlB + (size_t)nt * 512);
            acc[nt] = __builtin_amdgcn_mfma_f32_16x16x32_bf16(ah.v, bh, acc[nt], 0, 0, 0);
            acc[nt] = __builtin_amdgcn_mfma_f32_16x16x32_bf16(ah.v, bl, acc[nt], 0, 0, 0);
            acc[nt] = __builtin_amdgcn_mfma_f32_16x16x32_bf16(al.v, bh, acc[nt], 0, 0, 0);
        }
    }
}

__global__ __launch_bounds__(256) void gin_mlp_mfma(
    const float* __restrict__ Uin,
    const unsigned short* __restrict__ Wsw,
    const float* __restrict__ b1, const float* __restrict__ g1,
    const float* __restrict__ be1, const float* __restrict__ m1,
    const float* __restrict__ v1,
    const float* __restrict__ b2, const float* __restrict__ g2,
    const float* __restrict__ be2, const float* __restrict__ m2,
    const float* __restrict__ v2,
    int layer, int N, float* __restrict__ hout)
{
    __shared__ unsigned Up[64][132];                 // 33.8 KB packed hi|lo
    __shared__ float sc1[128], sh1[128], bs1[128];
    __shared__ float sc2[128], sh2[128], bs2[128];   // 3 KB epilogue params

    const int tid  = threadIdx.x;
    const int lane = tid & 63;
    const int wv   = tid >> 6;
    const int m0   = wv * 16;
    const int row0 = blockIdx.x * 64;

    if (tid < 128) {
        int c = tid;
        float s1v = g1[layer*D+c] * rsqrtf(v1[layer*D+c] + BN_EPS);
        sc1[c] = s1v; sh1[c] = be1[layer*D+c] - m1[layer*D+c] * s1v;
        bs1[c] = b1[layer*D+c];
        float s2v = g2[layer*D+c] * rsqrtf(v2[layer*D+c] + BN_EPS);
        sc2[c] = s2v; sh2[c] = be2[layer*D+c] - m2[layer*D+c] * s2v;
        bs2[c] = b2[layer*D+c];
    }

    // ---- stage U tile: fp32 global -> packed bf16 hi|lo in LDS ----
#pragma unroll
    for (int i = 0; i < 8; ++i) {
        int f4 = tid + 256 * i;
        int r  = f4 >> 5;
        int c  = (f4 & 31) << 2;
        int grow = row0 + r;
        float4 u = make_float4(0.f, 0.f, 0.f, 0.f);
        if (grow < N) u = *(const float4*)(Uin + (size_t)grow * D + c);
        uint4 q;
        q.x = packsplit(u.x); q.y = packsplit(u.y);
        q.z = packsplit(u.z); q.w = packsplit(u.w);
        *(uint4*)&Up[r][c] = q;
    }
    __syncthreads();

    f32x4 acc[8];
    const int col16 = lane & 15;
    const int quad  = lane >> 4;

    // ---- GEMM1 (g2s_hi = layer*4 + 0) + ReLU + BN1, repack into Up ----
    mfma_gemm16(Up, Wsw, layer * 4 + 0, bs1, m0, lane, acc);
#pragma unroll
    for (int nt = 0; nt < 8; ++nt) {
        int c = nt * 16 + col16;
        float s = sc1[c], t = sh1[c];
#pragma unroll
        for (int r = 0; r < 4; ++r) {
            float z = fmaf(fmaxf(acc[nt][r], 0.f), s, t);
            Up[m0 + quad * 4 + r][c] = packsplit(z);
        }
    }
    __syncthreads();   // safety: same-wave DS order would suffice; cheap

    // ---- GEMM2 (g2s_hi = layer*4 + 2) + BN2 + ReLU, store ----
    mfma_gemm16(Up, Wsw, layer * 4 + 2, bs2, m0, lane, acc);
#pragma unroll
    for (int nt = 0; nt < 8; ++nt) {
        int c = nt * 16 + col16;
        float s = sc2[c], t = sh2[c];
#pragma unroll
        for (int r = 0; r < 4; ++r) {
            int grow = row0 + m0 + quad * 4 + r;
            if (grow < N)
                hout[(size_t)grow * D + c] = fmaxf(fmaf(acc[nt][r], s, t), 0.f);
        }
    }
}

extern "C" void kernel_launch(void* const* d_in, const int* in_sizes, int n_in,
                              void* d_out, int out_size, void* d_ws, size_t ws_size,
                              hipStream_t stream)
{
    const float* x   = (const float*)d_in[0];
    const int*   ei  = (const int*)d_in[1];
    const float* W1  = (const float*)d_in[2];
    const float* b1  = (const float*)d_in[3];
    const float* g1  = (const float*)d_in[4];
    const float* be1 = (const float*)d_in[5];
    const float* m1  = (const float*)d_in[6];
    const float* v1  = (const float*)d_in[7];
    const float* W2  = (const float*)d_in[8];
    const float* b2  = (const float*)d_in[9];
    const float* eps = (const float*)d_in[10];
    const float* g2  = (const float*)d_in[11];
    const float* be2 = (const float*)d_in[12];
    const float* m2  = (const float*)d_in[13];
    const float* v2  = (const float*)d_in[14];

    const int N = in_sizes[0] / D;
    const int E = in_sizes[1] / 2;
    const int L = in_sizes[10];

    float* out = (float*)d_out;   // h lives here from layer 0 onward

    // ws layout: U | row_ptr | blk | fill_pos | col | Wsw
    float* U        = (float*)d_ws;
    int*   row_ptr  = (int*)(U + (size_t)N * D);
    int*   blk      = row_ptr + (N + 1);
    int*   fill_pos = blk + 2048;
    int*   col      = fill_pos + N;
    size_t off      = (size_t)((char*)(col + E) - (char*)d_ws);
    off = (off + 255) & ~(size_t)255;
    unsigned short* Wsw = (unsigned short*)((char*)d_ws + off);

    const int* src = ei;
    const int* dst = ei + E;

    const int NB = (N + SCAN_CHUNK - 1) / SCAN_CHUNK;

    // ---- weight pre-split + CSR build (once per launch) ----
    const int wtot = L * 2 * 4 * 8 * 64;
    w_split<<<(wtot + 255) / 256, 256, 0, stream>>>(W1, W2, Wsw, wtot);
    hipMemsetAsync(row_ptr, 0, (size_t)(N + 1 + 2048 + N) * sizeof(int), stream);
    csr_hist<<<(E + 255) / 256, 256, 0, stream>>>(dst, row_ptr, E);
    scan_pass_a<<<NB, SCAN_TPB, 0, stream>>>(row_ptr, blk, N);
    scan_pass_b<<<1, SCAN_TPB, 0, stream>>>(blk, NB);
    scan_pass_c<<<NB, SCAN_TPB, 0, stream>>>(row_ptr, blk, N, E);
    csr_fill<<<(E + 255) / 256, 256, 0, stream>>>(src, dst, row_ptr, fill_pos, col, E);

    // ---- layers: gather(h -> U), mfma-mlp(U -> h in d_out) ----
    const int gather_blocks = (N + 7) / 8;
    const int mlp_blocks    = (N + 63) / 64;
    const float* hin = x;
    for (int l = 0; l < L; ++l) {
        gin_gather<<<gather_blocks, 256, 0, stream>>>(hin, row_ptr, col, eps, l, U, N);
        gin_mlp_mfma<<<mlp_blocks, 256, 0, stream>>>(U, Wsw,
                                                     b1, g1, be1, m1, v1,
                                                     b2, g2, be2, m2, v2,
                                                     l, N, out);
        hin = out;
    }
}

// Round 6
// 596.616 us; speedup vs baseline: 9.6200x; 1.1433x over previous
//
#include <hip/hip_runtime.h>

#define D 128
#define BN_EPS 1e-5f
#define SCAN_TPB 256
#define SCAN_EPT 8
#define SCAN_CHUNK (SCAN_TPB * SCAN_EPT)

typedef __attribute__((ext_vector_type(8))) short bf16x8;
typedef __attribute__((ext_vector_type(4))) float f32x4;

__device__ __forceinline__ unsigned short f2bf_rn(float f) {
    unsigned u = __float_as_uint(f);
    u += 0x7FFFu + ((u >> 16) & 1u);
    return (unsigned short)(u >> 16);
}
// pack fp32 -> (bf16_hi << 16) | bf16_lo(residual)
__device__ __forceinline__ unsigned packsplit(float x) {
    unsigned short h = f2bf_rn(x);
    float r = x - __uint_as_float((unsigned)h << 16);
    return ((unsigned)h << 16) | (unsigned)f2bf_rn(r);
}

// ---------------------------------------------------------------------------
// CSR build: histogram -> exclusive scan -> fill (once per launch).
// ---------------------------------------------------------------------------
__global__ __launch_bounds__(256) void csr_hist(
    const int* __restrict__ dst, int* __restrict__ deg, int E)
{
    int e = blockIdx.x * 256 + threadIdx.x;
    if (e < E) atomicAdd(&deg[dst[e]], 1);
}

__global__ __launch_bounds__(SCAN_TPB) void scan_pass_a(
    int* __restrict__ data, int* __restrict__ blk, int n)
{
    __shared__ int s[SCAN_TPB];
    int tid  = threadIdx.x;
    int base = blockIdx.x * SCAN_CHUNK + tid * SCAN_EPT;
    int v[SCAN_EPT];
    int sum = 0;
#pragma unroll
    for (int i = 0; i < SCAN_EPT; ++i) {
        v[i] = (base + i < n) ? data[base + i] : 0;
        sum += v[i];
    }
    s[tid] = sum;
    __syncthreads();
#pragma unroll
    for (int off = 1; off < SCAN_TPB; off <<= 1) {
        int t = (tid >= off) ? s[tid - off] : 0;
        __syncthreads();
        s[tid] += t;
        __syncthreads();
    }
    int run = s[tid] - sum;
#pragma unroll
    for (int i = 0; i < SCAN_EPT; ++i) {
        if (base + i < n) data[base + i] = run;
        run += v[i];
    }
    if (tid == SCAN_TPB - 1) blk[blockIdx.x] = s[SCAN_TPB - 1];
}

__global__ __launch_bounds__(SCAN_TPB) void scan_pass_b(
    int* __restrict__ data, int n)
{
    __shared__ int s[SCAN_TPB];
    int tid  = threadIdx.x;
    int base = tid * SCAN_EPT;
    int v[SCAN_EPT];
    int sum = 0;
#pragma unroll
    for (int i = 0; i < SCAN_EPT; ++i) {
        v[i] = (base + i < n) ? data[base + i] : 0;
        sum += v[i];
    }
    s[tid] = sum;
    __syncthreads();
#pragma unroll
    for (int off = 1; off < SCAN_TPB; off <<= 1) {
        int t = (tid >= off) ? s[tid - off] : 0;
        __syncthreads();
        s[tid] += t;
        __syncthreads();
    }
    int run = s[tid] - sum;
#pragma unroll
    for (int i = 0; i < SCAN_EPT; ++i) {
        if (base + i < n) data[base + i] = run;
        run += v[i];
    }
}

__global__ __launch_bounds__(SCAN_TPB) void scan_pass_c(
    int* __restrict__ data, const int* __restrict__ blk, int n, int E)
{
    int base = blockIdx.x * SCAN_CHUNK + threadIdx.x * SCAN_EPT;
    int add  = blk[blockIdx.x];
#pragma unroll
    for (int i = 0; i < SCAN_EPT; ++i)
        if (base + i < n) data[base + i] += add;
    if (blockIdx.x == 0 && threadIdx.x == 0) data[n] = E;
}

__global__ __launch_bounds__(256) void csr_fill(
    const int* __restrict__ src, const int* __restrict__ dst,
    const int* __restrict__ row_ptr, int* __restrict__ fill_pos,
    int* __restrict__ col, int E)
{
    int e = blockIdx.x * 256 + threadIdx.x;
    if (e < E) {
        int d   = dst[e];
        int pos = atomicAdd(&fill_pos[d], 1);
        col[row_ptr[d] + pos] = src[e];
    }
}

// ---------------------------------------------------------------------------
// Weight pre-split (unchanged layout, verified in rounds 4-5).
// ---------------------------------------------------------------------------
__global__ __launch_bounds__(256) void w_split(
    const float* __restrict__ W1, const float* __restrict__ W2,
    unsigned short* __restrict__ Wsw, int total)
{
    int t = blockIdx.x * 256 + threadIdx.x;
    if (t >= total) return;                 // total = L*2*4*8*64
    int lane = t & 63;
    int nt   = (t >> 6) & 7;
    int ks   = (t >> 9) & 3;
    int g    = t >> 11;
    int layer = g >> 1, gemm = g & 1;
    const float* W = (gemm ? W2 : W1) + (size_t)layer * D * D;
    int n  = nt * 16 + (lane & 15);
    int kb = ks * 32 + (lane >> 4) * 8;
    union { unsigned short s[8]; uint4 q; } uh, ul;
#pragma unroll
    for (int j = 0; j < 8; ++j) {
        float x = W[(size_t)(kb + j) * D + n];
        unsigned short h = f2bf_rn(x);
        float r = x - __uint_as_float((unsigned)h << 16);
        uh.s[j] = h;
        ul.s[j] = f2bf_rn(r);
    }
    size_t ehi = ((((size_t)g * 2 + 0) * 4 + ks) * 8 + nt) * 512 + (size_t)lane * 8;
    size_t elo = ((((size_t)g * 2 + 1) * 4 + ks) * 8 + nt) * 512 + (size_t)lane * 8;
    *(uint4*)&Wsw[ehi] = uh.q;
    *(uint4*)&Wsw[elo] = ul.q;
}

// ---------------------------------------------------------------------------
// Layer-0 gather (fp32 x input): one row per half-wave, writes PACKED U.
// ---------------------------------------------------------------------------
__global__ __launch_bounds__(256) void gin_gather_f32(
    const float* __restrict__ h,
    const int* __restrict__ row_ptr, const int* __restrict__ col,
    const float* __restrict__ eps, int layer,
    unsigned* __restrict__ U, int N)
{
    int gid  = blockIdx.x * 256 + threadIdx.x;
    int row  = gid >> 5;
    int lane = threadIdx.x & 31;
    int c4   = lane << 2;
    if (row >= N) return;

    const float epsv = 1.0f + eps[layer];
    float4 acc;
    {
        float4 hv = *(const float4*)(h + (size_t)row * D + c4);
        acc.x = epsv * hv.x; acc.y = epsv * hv.y;
        acc.z = epsv * hv.z; acc.w = epsv * hv.w;
    }

    int j   = row_ptr[row];
    int end = row_ptr[row + 1];
    while (j < end) {
        int cnt = min(end - j, 32);
        int ci  = col[j + min(lane, cnt - 1)];
#pragma unroll 1
        for (int k = 0; k < cnt; k += 8) {
            int k0 = min(k + 0, cnt - 1), k1 = min(k + 1, cnt - 1);
            int k2 = min(k + 2, cnt - 1), k3 = min(k + 3, cnt - 1);
            int k4 = min(k + 4, cnt - 1), k5 = min(k + 5, cnt - 1);
            int k6 = min(k + 6, cnt - 1), k7 = min(k + 7, cnt - 1);
            int s0 = __shfl(ci, k0, 32), s1 = __shfl(ci, k1, 32);
            int s2 = __shfl(ci, k2, 32), s3 = __shfl(ci, k3, 32);
            int s4 = __shfl(ci, k4, 32), s5 = __shfl(ci, k5, 32);
            int s6 = __shfl(ci, k6, 32), s7 = __shfl(ci, k7, 32);
            float w1 = (k + 1 < cnt) ? 1.f : 0.f;
            float w2 = (k + 2 < cnt) ? 1.f : 0.f;
            float w3 = (k + 3 < cnt) ? 1.f : 0.f;
            float w4 = (k + 4 < cnt) ? 1.f : 0.f;
            float w5 = (k + 5 < cnt) ? 1.f : 0.f;
            float w6 = (k + 6 < cnt) ? 1.f : 0.f;
            float w7 = (k + 7 < cnt) ? 1.f : 0.f;
            float4 v0 = *(const float4*)(h + (size_t)s0 * D + c4);
            float4 v1 = *(const float4*)(h + (size_t)s1 * D + c4);
            float4 v2 = *(const float4*)(h + (size_t)s2 * D + c4);
            float4 v3 = *(const float4*)(h + (size_t)s3 * D + c4);
            float4 v4 = *(const float4*)(h + (size_t)s4 * D + c4);
            float4 v5 = *(const float4*)(h + (size_t)s5 * D + c4);
            float4 v6 = *(const float4*)(h + (size_t)s6 * D + c4);
            float4 v7 = *(const float4*)(h + (size_t)s7 * D + c4);
            acc.x += v0.x; acc.y += v0.y; acc.z += v0.z; acc.w += v0.w;
            acc.x = fmaf(w1, v1.x, acc.x); acc.y = fmaf(w1, v1.y, acc.y);
            acc.z = fmaf(w1, v1.z, acc.z); acc.w = fmaf(w1, v1.w, acc.w);
            acc.x = fmaf(w2, v2.x, acc.x); acc.y = fmaf(w2, v2.y, acc.y);
            acc.z = fmaf(w2, v2.z, acc.z); acc.w = fmaf(w2, v2.w, acc.w);
            acc.x = fmaf(w3, v3.x, acc.x); acc.y = fmaf(w3, v3.y, acc.y);
            acc.z = fmaf(w3, v3.z, acc.z); acc.w = fmaf(w3, v3.w, acc.w);
            acc.x = fmaf(w4, v4.x, acc.x); acc.y = fmaf(w4, v4.y, acc.y);
            acc.z = fmaf(w4, v4.z, acc.z); acc.w = fmaf(w4, v4.w, acc.w);
            acc.x = fmaf(w5, v5.x, acc.x); acc.y = fmaf(w5, v5.y, acc.y);
            acc.z = fmaf(w5, v5.z, acc.z); acc.w = fmaf(w5, v5.w, acc.w);
            acc.x = fmaf(w6, v6.x, acc.x); acc.y = fmaf(w6, v6.y, acc.y);
            acc.z = fmaf(w6, v6.z, acc.z); acc.w = fmaf(w6, v6.w, acc.w);
            acc.x = fmaf(w7, v7.x, acc.x); acc.y = fmaf(w7, v7.y, acc.y);
            acc.z = fmaf(w7, v7.z, acc.z); acc.w = fmaf(w7, v7.w, acc.w);
        }
        j += cnt;
    }

    uint4 q;
    q.x = packsplit(acc.x); q.y = packsplit(acc.y);
    q.z = packsplit(acc.z); q.w = packsplit(acc.w);
    *(uint4*)(U + (size_t)row * D + c4) = q;
}

// ---------------------------------------------------------------------------
// Layers 1+: gather from bf16 h (halved traffic). One row per 16 lanes
// (16 x 16B = one 256B row read). Writes packed U.
// ---------------------------------------------------------------------------
__device__ __forceinline__ void acc_bf8(float a[8], uint4 q, float w) {
    a[0] = fmaf(w, __uint_as_float(q.x << 16), a[0]);
    a[1] = fmaf(w, __uint_as_float(q.x & 0xffff0000u), a[1]);
    a[2] = fmaf(w, __uint_as_float(q.y << 16), a[2]);
    a[3] = fmaf(w, __uint_as_float(q.y & 0xffff0000u), a[3]);
    a[4] = fmaf(w, __uint_as_float(q.z << 16), a[4]);
    a[5] = fmaf(w, __uint_as_float(q.z & 0xffff0000u), a[5]);
    a[6] = fmaf(w, __uint_as_float(q.w << 16), a[6]);
    a[7] = fmaf(w, __uint_as_float(q.w & 0xffff0000u), a[7]);
}

__global__ __launch_bounds__(256) void gin_gather_bf16(
    const unsigned short* __restrict__ h,
    const int* __restrict__ row_ptr, const int* __restrict__ col,
    const float* __restrict__ eps, int layer,
    unsigned* __restrict__ U, int N)
{
    int gid  = blockIdx.x * 256 + threadIdx.x;
    int row  = gid >> 4;
    int l16  = threadIdx.x & 15;
    int c8   = l16 << 3;                 // 8 bf16 elements per lane
    if (row >= N) return;

    const float epsv = 1.0f + eps[layer];
    float a[8];
    {
        uint4 q = *(const uint4*)(h + (size_t)row * D + c8);
        a[0] = a[1] = a[2] = a[3] = a[4] = a[5] = a[6] = a[7] = 0.f;
        acc_bf8(a, q, epsv);
    }

    int j   = row_ptr[row];
    int end = row_ptr[row + 1];
    while (j < end) {
        int cnt = min(end - j, 16);
        int ci  = col[j + min(l16, cnt - 1)];
#pragma unroll 1
        for (int k = 0; k < cnt; k += 8) {
            int k0 = min(k + 0, cnt - 1), k1 = min(k + 1, cnt - 1);
            int k2 = min(k + 2, cnt - 1), k3 = min(k + 3, cnt - 1);
            int k4 = min(k + 4, cnt - 1), k5 = min(k + 5, cnt - 1);
            int k6 = min(k + 6, cnt - 1), k7 = min(k + 7, cnt - 1);
            int s0 = __shfl(ci, k0, 16), s1 = __shfl(ci, k1, 16);
            int s2 = __shfl(ci, k2, 16), s3 = __shfl(ci, k3, 16);
            int s4 = __shfl(ci, k4, 16), s5 = __shfl(ci, k5, 16);
            int s6 = __shfl(ci, k6, 16), s7 = __shfl(ci, k7, 16);
            float w1 = (k + 1 < cnt) ? 1.f : 0.f;
            float w2 = (k + 2 < cnt) ? 1.f : 0.f;
            float w3 = (k + 3 < cnt) ? 1.f : 0.f;
            float w4 = (k + 4 < cnt) ? 1.f : 0.f;
            float w5 = (k + 5 < cnt) ? 1.f : 0.f;
            float w6 = (k + 6 < cnt) ? 1.f : 0.f;
            float w7 = (k + 7 < cnt) ? 1.f : 0.f;
            uint4 q0 = *(const uint4*)(h + (size_t)s0 * D + c8);
            uint4 q1 = *(const uint4*)(h + (size_t)s1 * D + c8);
            uint4 q2 = *(const uint4*)(h + (size_t)s2 * D + c8);
            uint4 q3 = *(const uint4*)(h + (size_t)s3 * D + c8);
            uint4 q4 = *(const uint4*)(h + (size_t)s4 * D + c8);
            uint4 q5 = *(const uint4*)(h + (size_t)s5 * D + c8);
            uint4 q6 = *(const uint4*)(h + (size_t)s6 * D + c8);
            uint4 q7 = *(const uint4*)(h + (size_t)s7 * D + c8);
            acc_bf8(a, q0, 1.f);
            acc_bf8(a, q1, w1);
            acc_bf8(a, q2, w2);
            acc_bf8(a, q3, w3);
            acc_bf8(a, q4, w4);
            acc_bf8(a, q5, w5);
            acc_bf8(a, q6, w6);
            acc_bf8(a, q7, w7);
        }
        j += cnt;
    }

    uint4 o0, o1;
    o0.x = packsplit(a[0]); o0.y = packsplit(a[1]);
    o0.z = packsplit(a[2]); o0.w = packsplit(a[3]);
    o1.x = packsplit(a[4]); o1.y = packsplit(a[5]);
    o1.z = packsplit(a[6]); o1.w = packsplit(a[7]);
    *(uint4*)(U + (size_t)row * D + c8)     = o0;
    *(uint4*)(U + (size_t)row * D + c8 + 4) = o1;
}

// ---------------------------------------------------------------------------
// MFMA MLP. Block = 256 thr = 4 waves; block tile M=128, each wave owns TWO
// 16-row strips (M=32) -> halves B-frag traffic, doubles MFMA per B-load.
// Up (LDS) holds packed hi|lo activations, stride 132. 3 MFMAs per site.
// ---------------------------------------------------------------------------
__device__ __forceinline__ void mfma_gemm32(
    const unsigned (*Up)[132], const unsigned short* __restrict__ Wsw,
    int g2s_hi, const float* __restrict__ bsLDS,
    int m0, int lane, f32x4 acc0[8], f32x4 acc1[8])
{
    const int col16 = lane & 15;
    const int quad  = lane >> 4;
#pragma unroll
    for (int nt = 0; nt < 8; ++nt) {
        float b = bsLDS[nt * 16 + col16];
        acc0[nt][0] = b; acc0[nt][1] = b; acc0[nt][2] = b; acc0[nt][3] = b;
        acc1[nt][0] = b; acc1[nt][1] = b; acc1[nt][2] = b; acc1[nt][3] = b;
    }
    const int r0 = m0 + col16;
#pragma unroll
    for (int ks = 0; ks < 4; ++ks) {
        const int kb = ks * 32 + quad * 8;
        uint4 p0 = *(const uint4*)&Up[r0][kb];
        uint4 p1 = *(const uint4*)&Up[r0][kb + 4];
        uint4 p2 = *(const uint4*)&Up[r0 + 16][kb];
        uint4 p3 = *(const uint4*)&Up[r0 + 16][kb + 4];
        unsigned pa[8] = {p0.x, p0.y, p0.z, p0.w, p1.x, p1.y, p1.z, p1.w};
        unsigned pb[8] = {p2.x, p2.y, p2.z, p2.w, p3.x, p3.y, p3.z, p3.w};
        union { unsigned u[4]; bf16x8 v; } ah0, al0, ah1, al1;
#pragma unroll
        for (int j = 0; j < 4; ++j) {
            ah0.u[j] = (pa[2*j] >> 16)     | (pa[2*j+1] & 0xFFFF0000u);
            al0.u[j] = (pa[2*j] & 0xFFFFu) | (pa[2*j+1] << 16);
            ah1.u[j] = (pb[2*j] >> 16)     | (pb[2*j+1] & 0xFFFF0000u);
            al1.u[j] = (pb[2*j] & 0xFFFFu) | (pb[2*j+1] << 16);
        }
        const unsigned short* whB =
            Wsw + ((((size_t)g2s_hi)     * 4 + ks) * 8) * 512 + (size_t)lane * 8;
        const unsigned short* wlB =
            Wsw + ((((size_t)g2s_hi + 1) * 4 + ks) * 8) * 512 + (size_t)lane * 8;
#pragma unroll
        for (int nt = 0; nt < 8; ++nt) {
            bf16x8 bh = *(const bf16x8*)(whB + (size_t)nt * 512);
            bf16x8 bl = *(const bf16x8*)(wlB + (size_t)nt * 512);
            acc0[nt] = __builtin_amdgcn_mfma_f32_16x16x32_bf16(ah0.v, bh, acc0[nt], 0, 0, 0);
            acc0[nt] = __builtin_amdgcn_mfma_f32_16x16x32_bf16(ah0.v, bl, acc0[nt], 0, 0, 0);
            acc0[nt] = __builtin_amdgcn_mfma_f32_16x16x32_bf16(al0.v, bh, acc0[nt], 0, 0, 0);
            acc1[nt] = __builtin_amdgcn_mfma_f32_16x16x32_bf16(ah1.v, bh, acc1[nt], 0, 0, 0);
            acc1[nt] = __builtin_amdgcn_mfma_f32_16x16x32_bf16(ah1.v, bl, acc1[nt], 0, 0, 0);
            acc1[nt] = __builtin_amdgcn_mfma_f32_16x16x32_bf16(al1.v, bh, acc1[nt], 0, 0, 0);
        }
    }
}

__global__ __launch_bounds__(256) void gin_mlp_mfma(
    const unsigned* __restrict__ Uin,
    const unsigned short* __restrict__ Wsw,
    const float* __restrict__ b1, const float* __restrict__ g1,
    const float* __restrict__ be1, const float* __restrict__ m1,
    const float* __restrict__ v1,
    const float* __restrict__ b2, const float* __restrict__ g2,
    const float* __restrict__ be2, const float* __restrict__ m2,
    const float* __restrict__ v2,
    int layer, int N, int last,
    unsigned short* __restrict__ hout_bf, float* __restrict__ hout_f)
{
    __shared__ unsigned Up[128][132];                // 67.6 KB packed hi|lo
    __shared__ float sc1[128], sh1[128], bs1[128];
    __shared__ float sc2[128], sh2[128], bs2[128];

    const int tid  = threadIdx.x;
    const int lane = tid & 63;
    const int wv   = tid >> 6;
    const int m0   = wv * 32;
    const int row0 = blockIdx.x * 128;

    if (tid < 128) {
        int c = tid;
        float s1v = g1[layer*D+c] * rsqrtf(v1[layer*D+c] + BN_EPS);
        sc1[c] = s1v; sh1[c] = be1[layer*D+c] - m1[layer*D+c] * s1v;
        bs1[c] = b1[layer*D+c];
        float s2v = g2[layer*D+c] * rsqrtf(v2[layer*D+c] + BN_EPS);
        sc2[c] = s2v; sh2[c] = be2[layer*D+c] - m2[layer*D+c] * s2v;
        bs2[c] = b2[layer*D+c];
    }

    // ---- stage packed U tile (pure copy, coalesced) ----
#pragma unroll
    for (int i = 0; i < 16; ++i) {
        int f4 = tid + 256 * i;
        int r  = f4 >> 5;
        int c  = (f4 & 31) << 2;
        int grow = row0 + r;
        uint4 q = make_uint4(0, 0, 0, 0);
        if (grow < N) q = *(const uint4*)(Uin + (size_t)grow * D + c);
        *(uint4*)&Up[r][c] = q;
    }
    __syncthreads();

    f32x4 acc0[8], acc1[8];
    const int col16 = lane & 15;
    const int quad  = lane >> 4;

    // ---- GEMM1 + ReLU + BN1, repack into Up ----
    mfma_gemm32(Up, Wsw, layer * 4 + 0, bs1, m0, lane, acc0, acc1);
#pragma unroll
    for (int nt = 0; nt < 8; ++nt) {
        int c = nt * 16 + col16;
        float s = sc1[c], t = sh1[c];
#pragma unroll
        for (int r = 0; r < 4; ++r) {
            Up[m0 + quad * 4 + r][c]      = packsplit(fmaf(fmaxf(acc0[nt][r], 0.f), s, t));
            Up[m0 + 16 + quad * 4 + r][c] = packsplit(fmaf(fmaxf(acc1[nt][r], 0.f), s, t));
        }
    }
    __syncthreads();

    // ---- GEMM2 + BN2 + ReLU, store (bf16 intermediate / fp32 final) ----
    mfma_gemm32(Up, Wsw, layer * 4 + 2, bs2, m0, lane, acc0, acc1);
#pragma unroll
    for (int nt = 0; nt < 8; ++nt) {
        int c = nt * 16 + col16;
        float s = sc2[c], t = sh2[c];
#pragma unroll
        for (int r = 0; r < 4; ++r) {
            int gr0 = row0 + m0 + quad * 4 + r;
            int gr1 = gr0 + 16;
            float o0 = fmaxf(fmaf(acc0[nt][r], s, t), 0.f);
            float o1 = fmaxf(fmaf(acc1[nt][r], s, t), 0.f);
            if (last) {
                if (gr0 < N) hout_f[(size_t)gr0 * D + c] = o0;
                if (gr1 < N) hout_f[(size_t)gr1 * D + c] = o1;
            } else {
                if (gr0 < N) hout_bf[(size_t)gr0 * D + c] = f2bf_rn(o0);
                if (gr1 < N) hout_bf[(size_t)gr1 * D + c] = f2bf_rn(o1);
            }
        }
    }
}

extern "C" void kernel_launch(void* const* d_in, const int* in_sizes, int n_in,
                              void* d_out, int out_size, void* d_ws, size_t ws_size,
                              hipStream_t stream)
{
    const float* x   = (const float*)d_in[0];
    const int*   ei  = (const int*)d_in[1];
    const float* W1  = (const float*)d_in[2];
    const float* b1  = (const float*)d_in[3];
    const float* g1  = (const float*)d_in[4];
    const float* be1 = (const float*)d_in[5];
    const float* m1  = (const float*)d_in[6];
    const float* v1  = (const float*)d_in[7];
    const float* W2  = (const float*)d_in[8];
    const float* b2  = (const float*)d_in[9];
    const float* eps = (const float*)d_in[10];
    const float* g2  = (const float*)d_in[11];
    const float* be2 = (const float*)d_in[12];
    const float* m2  = (const float*)d_in[13];
    const float* v2  = (const float*)d_in[14];

    const int N = in_sizes[0] / D;
    const int E = in_sizes[1] / 2;
    const int L = in_sizes[10];

    float*          out = (float*)d_out;
    unsigned short* hb  = (unsigned short*)d_out;   // bf16 h lives in d_out's
                                                    // first half; dead before the
                                                    // final fp32 write clobbers it

    // ws layout: U(packed) | row_ptr | blk | fill_pos | col | Wsw  (~54.7 MB)
    unsigned* U        = (unsigned*)d_ws;
    int*      row_ptr  = (int*)(U + (size_t)N * D);
    int*      blk      = row_ptr + (N + 1);
    int*      fill_pos = blk + 2048;
    int*      col      = fill_pos + N;
    size_t off = (size_t)((char*)(col + E) - (char*)d_ws);
    off = (off + 255) & ~(size_t)255;
    unsigned short* Wsw = (unsigned short*)((char*)d_ws + off);

    const int* src = ei;
    const int* dst = ei + E;

    const int NB = (N + SCAN_CHUNK - 1) / SCAN_CHUNK;

    // ---- weight pre-split + CSR build (once per launch) ----
    const int wtot = L * 2 * 4 * 8 * 64;
    w_split<<<(wtot + 255) / 256, 256, 0, stream>>>(W1, W2, Wsw, wtot);
    hipMemsetAsync(row_ptr, 0, (size_t)(N + 1 + 2048 + N) * sizeof(int), stream);
    csr_hist<<<(E + 255) / 256, 256, 0, stream>>>(dst, row_ptr, E);
    scan_pass_a<<<NB, SCAN_TPB, 0, stream>>>(row_ptr, blk, N);
    scan_pass_b<<<1, SCAN_TPB, 0, stream>>>(blk, NB);
    scan_pass_c<<<NB, SCAN_TPB, 0, stream>>>(row_ptr, blk, N, E);
    csr_fill<<<(E + 255) / 256, 256, 0, stream>>>(src, dst, row_ptr, fill_pos, col, E);

    // ---- layers ----
    const int mlp_blocks = (N + 127) / 128;
    for (int l = 0; l < L; ++l) {
        if (l == 0)
            gin_gather_f32<<<(N + 7) / 8, 256, 0, stream>>>(x, row_ptr, col, eps, l, U, N);
        else
            gin_gather_bf16<<<(N + 15) / 16, 256, 0, stream>>>(hb, row_ptr, col, eps, l, U, N);
        gin_mlp_mfma<<<mlp_blocks, 256, 0, stream>>>(U, Wsw,
                                                     b1, g1, be1, m1, v1,
                                                     b2, g2, be2, m2, v2,
                                                     l, N, (l == L - 1) ? 1 : 0,
                                                     hb, out);
    }
}

// Round 7
// 577.911 us; speedup vs baseline: 9.9314x; 1.0324x over previous
//
#include <hip/hip_runtime.h>

#define D 128
#define BN_EPS 1e-5f
#define SCAN_TPB 256
#define SCAN_EPT 8
#define SCAN_CHUNK (SCAN_TPB * SCAN_EPT)

typedef __attribute__((ext_vector_type(8))) short bf16x8;
typedef __attribute__((ext_vector_type(4))) float f32x4;

__device__ __forceinline__ unsigned short f2bf_rn(float f) {
    unsigned u = __float_as_uint(f);
    u += 0x7FFFu + ((u >> 16) & 1u);
    return (unsigned short)(u >> 16);
}

// ---------------------------------------------------------------------------
// CSR build: histogram -> exclusive scan -> fill (once per launch).
// ---------------------------------------------------------------------------
__global__ __launch_bounds__(256) void csr_hist(
    const int* __restrict__ dst, int* __restrict__ deg, int E)
{
    int e = blockIdx.x * 256 + threadIdx.x;
    if (e < E) atomicAdd(&deg[dst[e]], 1);
}

__global__ __launch_bounds__(SCAN_TPB) void scan_pass_a(
    int* __restrict__ data, int* __restrict__ blk, int n)
{
    __shared__ int s[SCAN_TPB];
    int tid  = threadIdx.x;
    int base = blockIdx.x * SCAN_CHUNK + tid * SCAN_EPT;
    int v[SCAN_EPT];
    int sum = 0;
#pragma unroll
    for (int i = 0; i < SCAN_EPT; ++i) {
        v[i] = (base + i < n) ? data[base + i] : 0;
        sum += v[i];
    }
    s[tid] = sum;
    __syncthreads();
#pragma unroll
    for (int off = 1; off < SCAN_TPB; off <<= 1) {
        int t = (tid >= off) ? s[tid - off] : 0;
        __syncthreads();
        s[tid] += t;
        __syncthreads();
    }
    int run = s[tid] - sum;
#pragma unroll
    for (int i = 0; i < SCAN_EPT; ++i) {
        if (base + i < n) data[base + i] = run;
        run += v[i];
    }
    if (tid == SCAN_TPB - 1) blk[blockIdx.x] = s[SCAN_TPB - 1];
}

__global__ __launch_bounds__(SCAN_TPB) void scan_pass_b(
    int* __restrict__ data, int n)
{
    __shared__ int s[SCAN_TPB];
    int tid  = threadIdx.x;
    int base = tid * SCAN_EPT;
    int v[SCAN_EPT];
    int sum = 0;
#pragma unroll
    for (int i = 0; i < SCAN_EPT; ++i) {
        v[i] = (base + i < n) ? data[base + i] : 0;
        sum += v[i];
    }
    s[tid] = sum;
    __syncthreads();
#pragma unroll
    for (int off = 1; off < SCAN_TPB; off <<= 1) {
        int t = (tid >= off) ? s[tid - off] : 0;
        __syncthreads();
        s[tid] += t;
        __syncthreads();
    }
    int run = s[tid] - sum;
#pragma unroll
    for (int i = 0; i < SCAN_EPT; ++i) {
        if (base + i < n) data[base + i] = run;
        run += v[i];
    }
}

__global__ __launch_bounds__(SCAN_TPB) void scan_pass_c(
    int* __restrict__ data, const int* __restrict__ blk, int n, int E)
{
    int base = blockIdx.x * SCAN_CHUNK + threadIdx.x * SCAN_EPT;
    int add  = blk[blockIdx.x];
#pragma unroll
    for (int i = 0; i < SCAN_EPT; ++i)
        if (base + i < n) data[base + i] += add;
    if (blockIdx.x == 0 && threadIdx.x == 0) data[n] = E;
}

__global__ __launch_bounds__(256) void csr_fill(
    const int* __restrict__ src, const int* __restrict__ dst,
    const int* __restrict__ row_ptr, int* __restrict__ fill_pos,
    int* __restrict__ col, int E)
{
    int e = blockIdx.x * 256 + threadIdx.x;
    if (e < E) {
        int d   = dst[e];
        int pos = atomicAdd(&fill_pos[d], 1);
        col[row_ptr[d] + pos] = src[e];
    }
}

// ---------------------------------------------------------------------------
// Weight pre-split: fp32 W -> bf16 hi/lo in MFMA B-fragment order (verified
// layout, rounds 4-6). Weights keep hi+lo; only activations drop lo.
// ---------------------------------------------------------------------------
__global__ __launch_bounds__(256) void w_split(
    const float* __restrict__ W1, const float* __restrict__ W2,
    unsigned short* __restrict__ Wsw, int total)
{
    int t = blockIdx.x * 256 + threadIdx.x;
    if (t >= total) return;                 // total = L*2*4*8*64
    int lane = t & 63;
    int nt   = (t >> 6) & 7;
    int ks   = (t >> 9) & 3;
    int g    = t >> 11;
    int layer = g >> 1, gemm = g & 1;
    const float* W = (gemm ? W2 : W1) + (size_t)layer * D * D;
    int n  = nt * 16 + (lane & 15);
    int kb = ks * 32 + (lane >> 4) * 8;
    union { unsigned short s[8]; uint4 q; } uh, ul;
#pragma unroll
    for (int j = 0; j < 8; ++j) {
        float x = W[(size_t)(kb + j) * D + n];
        unsigned short h = f2bf_rn(x);
        float r = x - __uint_as_float((unsigned)h << 16);
        uh.s[j] = h;
        ul.s[j] = f2bf_rn(r);
    }
    size_t ehi = ((((size_t)g * 2 + 0) * 4 + ks) * 8 + nt) * 512 + (size_t)lane * 8;
    size_t elo = ((((size_t)g * 2 + 1) * 4 + ks) * 8 + nt) * 512 + (size_t)lane * 8;
    *(uint4*)&Wsw[ehi] = uh.q;
    *(uint4*)&Wsw[elo] = ul.q;
}

// ---------------------------------------------------------------------------
// Layer-0 gather (fp32 x input): one row per half-wave, writes bf16 U.
// ---------------------------------------------------------------------------
__global__ __launch_bounds__(256) void gin_gather_f32(
    const float* __restrict__ h,
    const int* __restrict__ row_ptr, const int* __restrict__ col,
    const float* __restrict__ eps, int layer,
    unsigned short* __restrict__ U, int N)
{
    int gid  = blockIdx.x * 256 + threadIdx.x;
    int row  = gid >> 5;
    int lane = threadIdx.x & 31;
    int c4   = lane << 2;
    if (row >= N) return;

    const float epsv = 1.0f + eps[layer];
    float4 acc;
    {
        float4 hv = *(const float4*)(h + (size_t)row * D + c4);
        acc.x = epsv * hv.x; acc.y = epsv * hv.y;
        acc.z = epsv * hv.z; acc.w = epsv * hv.w;
    }

    int j   = row_ptr[row];
    int end = row_ptr[row + 1];
    while (j < end) {
        int cnt = min(end - j, 32);
        int ci  = col[j + min(lane, cnt - 1)];
#pragma unroll 1
        for (int k = 0; k < cnt; k += 8) {
            int k0 = min(k + 0, cnt - 1), k1 = min(k + 1, cnt - 1);
            int k2 = min(k + 2, cnt - 1), k3 = min(k + 3, cnt - 1);
            int k4 = min(k + 4, cnt - 1), k5 = min(k + 5, cnt - 1);
            int k6 = min(k + 6, cnt - 1), k7 = min(k + 7, cnt - 1);
            int s0 = __shfl(ci, k0, 32), s1 = __shfl(ci, k1, 32);
            int s2 = __shfl(ci, k2, 32), s3 = __shfl(ci, k3, 32);
            int s4 = __shfl(ci, k4, 32), s5 = __shfl(ci, k5, 32);
            int s6 = __shfl(ci, k6, 32), s7 = __shfl(ci, k7, 32);
            float w1 = (k + 1 < cnt) ? 1.f : 0.f;
            float w2 = (k + 2 < cnt) ? 1.f : 0.f;
            float w3 = (k + 3 < cnt) ? 1.f : 0.f;
            float w4 = (k + 4 < cnt) ? 1.f : 0.f;
            float w5 = (k + 5 < cnt) ? 1.f : 0.f;
            float w6 = (k + 6 < cnt) ? 1.f : 0.f;
            float w7 = (k + 7 < cnt) ? 1.f : 0.f;
            float4 v0 = *(const float4*)(h + (size_t)s0 * D + c4);
            float4 v1 = *(const float4*)(h + (size_t)s1 * D + c4);
            float4 v2 = *(const float4*)(h + (size_t)s2 * D + c4);
            float4 v3 = *(const float4*)(h + (size_t)s3 * D + c4);
            float4 v4 = *(const float4*)(h + (size_t)s4 * D + c4);
            float4 v5 = *(const float4*)(h + (size_t)s5 * D + c4);
            float4 v6 = *(const float4*)(h + (size_t)s6 * D + c4);
            float4 v7 = *(const float4*)(h + (size_t)s7 * D + c4);
            acc.x += v0.x; acc.y += v0.y; acc.z += v0.z; acc.w += v0.w;
            acc.x = fmaf(w1, v1.x, acc.x); acc.y = fmaf(w1, v1.y, acc.y);
            acc.z = fmaf(w1, v1.z, acc.z); acc.w = fmaf(w1, v1.w, acc.w);
            acc.x = fmaf(w2, v2.x, acc.x); acc.y = fmaf(w2, v2.y, acc.y);
            acc.z = fmaf(w2, v2.z, acc.z); acc.w = fmaf(w2, v2.w, acc.w);
            acc.x = fmaf(w3, v3.x, acc.x); acc.y = fmaf(w3, v3.y, acc.y);
            acc.z = fmaf(w3, v3.z, acc.z); acc.w = fmaf(w3, v3.w, acc.w);
            acc.x = fmaf(w4, v4.x, acc.x); acc.y = fmaf(w4, v4.y, acc.y);
            acc.z = fmaf(w4, v4.z, acc.z); acc.w = fmaf(w4, v4.w, acc.w);
            acc.x = fmaf(w5, v5.x, acc.x); acc.y = fmaf(w5, v5.y, acc.y);
            acc.z = fmaf(w5, v5.z, acc.z); acc.w = fmaf(w5, v5.w, acc.w);
            acc.x = fmaf(w6, v6.x, acc.x); acc.y = fmaf(w6, v6.y, acc.y);
            acc.z = fmaf(w6, v6.z, acc.z); acc.w = fmaf(w6, v6.w, acc.w);
            acc.x = fmaf(w7, v7.x, acc.x); acc.y = fmaf(w7, v7.y, acc.y);
            acc.z = fmaf(w7, v7.z, acc.z); acc.w = fmaf(w7, v7.w, acc.w);
        }
        j += cnt;
    }

    ushort4 o;
    o.x = f2bf_rn(acc.x); o.y = f2bf_rn(acc.y);
    o.z = f2bf_rn(acc.z); o.w = f2bf_rn(acc.w);
    *(ushort4*)(U + (size_t)row * D + c4) = o;
}

// ---------------------------------------------------------------------------
// Layers 1+: gather from bf16 h. One row per 16 lanes (16 x 16B row read).
// Writes bf16 U.
// ---------------------------------------------------------------------------
__device__ __forceinline__ void acc_bf8(float a[8], uint4 q, float w) {
    a[0] = fmaf(w, __uint_as_float(q.x << 16), a[0]);
    a[1] = fmaf(w, __uint_as_float(q.x & 0xffff0000u), a[1]);
    a[2] = fmaf(w, __uint_as_float(q.y << 16), a[2]);
    a[3] = fmaf(w, __uint_as_float(q.y & 0xffff0000u), a[3]);
    a[4] = fmaf(w, __uint_as_float(q.z << 16), a[4]);
    a[5] = fmaf(w, __uint_as_float(q.z & 0xffff0000u), a[5]);
    a[6] = fmaf(w, __uint_as_float(q.w << 16), a[6]);
    a[7] = fmaf(w, __uint_as_float(q.w & 0xffff0000u), a[7]);
}

__global__ __launch_bounds__(256) void gin_gather_bf16(
    const unsigned short* __restrict__ h,
    const int* __restrict__ row_ptr, const int* __restrict__ col,
    const float* __restrict__ eps, int layer,
    unsigned short* __restrict__ U, int N)
{
    int gid  = blockIdx.x * 256 + threadIdx.x;
    int row  = gid >> 4;
    int l16  = threadIdx.x & 15;
    int c8   = l16 << 3;
    if (row >= N) return;

    const float epsv = 1.0f + eps[layer];
    float a[8];
    {
        uint4 q = *(const uint4*)(h + (size_t)row * D + c8);
        a[0] = a[1] = a[2] = a[3] = a[4] = a[5] = a[6] = a[7] = 0.f;
        acc_bf8(a, q, epsv);
    }

    int j   = row_ptr[row];
    int end = row_ptr[row + 1];
    while (j < end) {
        int cnt = min(end - j, 16);
        int ci  = col[j + min(l16, cnt - 1)];
#pragma unroll 1
        for (int k = 0; k < cnt; k += 8) {
            int k0 = min(k + 0, cnt - 1), k1 = min(k + 1, cnt - 1);
            int k2 = min(k + 2, cnt - 1), k3 = min(k + 3, cnt - 1);
            int k4 = min(k + 4, cnt - 1), k5 = min(k + 5, cnt - 1);
            int k6 = min(k + 6, cnt - 1), k7 = min(k + 7, cnt - 1);
            int s0 = __shfl(ci, k0, 16), s1 = __shfl(ci, k1, 16);
            int s2 = __shfl(ci, k2, 16), s3 = __shfl(ci, k3, 16);
            int s4 = __shfl(ci, k4, 16), s5 = __shfl(ci, k5, 16);
            int s6 = __shfl(ci, k6, 16), s7 = __shfl(ci, k7, 16);
            float w1 = (k + 1 < cnt) ? 1.f : 0.f;
            float w2 = (k + 2 < cnt) ? 1.f : 0.f;
            float w3 = (k + 3 < cnt) ? 1.f : 0.f;
            float w4 = (k + 4 < cnt) ? 1.f : 0.f;
            float w5 = (k + 5 < cnt) ? 1.f : 0.f;
            float w6 = (k + 6 < cnt) ? 1.f : 0.f;
            float w7 = (k + 7 < cnt) ? 1.f : 0.f;
            uint4 q0 = *(const uint4*)(h + (size_t)s0 * D + c8);
            uint4 q1 = *(const uint4*)(h + (size_t)s1 * D + c8);
            uint4 q2 = *(const uint4*)(h + (size_t)s2 * D + c8);
            uint4 q3 = *(const uint4*)(h + (size_t)s3 * D + c8);
            uint4 q4 = *(const uint4*)(h + (size_t)s4 * D + c8);
            uint4 q5 = *(const uint4*)(h + (size_t)s5 * D + c8);
            uint4 q6 = *(const uint4*)(h + (size_t)s6 * D + c8);
            uint4 q7 = *(const uint4*)(h + (size_t)s7 * D + c8);
            acc_bf8(a, q0, 1.f);
            acc_bf8(a, q1, w1);
            acc_bf8(a, q2, w2);
            acc_bf8(a, q3, w3);
            acc_bf8(a, q4, w4);
            acc_bf8(a, q5, w5);
            acc_bf8(a, q6, w6);
            acc_bf8(a, q7, w7);
        }
        j += cnt;
    }

    union { unsigned short s[8]; uint4 q; } o;
#pragma unroll
    for (int i = 0; i < 8; ++i) o.s[i] = f2bf_rn(a[i]);
    *(uint4*)(U + (size_t)row * D + c8) = o.q;
}

// ---------------------------------------------------------------------------
// MFMA MLP. Block = 256 thr = 4 waves, tile M=128, each wave owns two 16-row
// strips. Up LDS is plain bf16, stride 136 shorts (=272B: 16B-aligned b128
// reads, 2-way bank alias = free). A-frag = ONE ds_read_b128, no unpack.
// Weights hi+lo -> 2 MFMAs per site. LDS 37.8 KB -> 4 blocks/CU.
// ---------------------------------------------------------------------------
__device__ __forceinline__ void mfma_gemm32(
    const unsigned short (*Up)[136], const unsigned short* __restrict__ Wsw,
    int g2s_hi, const float* __restrict__ bsLDS,
    int m0, int lane, f32x4 acc0[8], f32x4 acc1[8])
{
    const int col16 = lane & 15;
    const int quad  = lane >> 4;
#pragma unroll
    for (int nt = 0; nt < 8; ++nt) {
        float b = bsLDS[nt * 16 + col16];
        acc0[nt][0] = b; acc0[nt][1] = b; acc0[nt][2] = b; acc0[nt][3] = b;
        acc1[nt][0] = b; acc1[nt][1] = b; acc1[nt][2] = b; acc1[nt][3] = b;
    }
    const int r0 = m0 + col16;
#pragma unroll
    for (int ks = 0; ks < 4; ++ks) {
        const int kb = ks * 32 + quad * 8;
        bf16x8 a0 = *(const bf16x8*)&Up[r0][kb];
        bf16x8 a1 = *(const bf16x8*)&Up[r0 + 16][kb];
        const unsigned short* whB =
            Wsw + ((((size_t)g2s_hi)     * 4 + ks) * 8) * 512 + (size_t)lane * 8;
        const unsigned short* wlB =
            Wsw + ((((size_t)g2s_hi + 1) * 4 + ks) * 8) * 512 + (size_t)lane * 8;
#pragma unroll
        for (int nt = 0; nt < 8; ++nt) {
            bf16x8 bh = *(const bf16x8*)(whB + (size_t)nt * 512);
            bf16x8 bl = *(const bf16x8*)(wlB + (size_t)nt * 512);
            acc0[nt] = __builtin_amdgcn_mfma_f32_16x16x32_bf16(a0, bh, acc0[nt], 0, 0, 0);
            acc0[nt] = __builtin_amdgcn_mfma_f32_16x16x32_bf16(a0, bl, acc0[nt], 0, 0, 0);
            acc1[nt] = __builtin_amdgcn_mfma_f32_16x16x32_bf16(a1, bh, acc1[nt], 0, 0, 0);
            acc1[nt] = __builtin_amdgcn_mfma_f32_16x16x32_bf16(a1, bl, acc1[nt], 0, 0, 0);
        }
    }
}

__global__ __launch_bounds__(256) void gin_mlp_mfma(
    const unsigned short* __restrict__ Uin,
    const unsigned short* __restrict__ Wsw,
    const float* __restrict__ b1, const float* __restrict__ g1,
    const float* __restrict__ be1, const float* __restrict__ m1,
    const float* __restrict__ v1,
    const float* __restrict__ b2, const float* __restrict__ g2,
    const float* __restrict__ be2, const float* __restrict__ m2,
    const float* __restrict__ v2,
    int layer, int N, int last,
    unsigned short* __restrict__ hout_bf, float* __restrict__ hout_f)
{
    __shared__ unsigned short Up[128][136];          // 34.8 KB bf16
    __shared__ float sc1[128], sh1[128], bs1[128];
    __shared__ float sc2[128], sh2[128], bs2[128];

    const int tid  = threadIdx.x;
    const int lane = tid & 63;
    const int wv   = tid >> 6;
    const int m0   = wv * 32;
    const int row0 = blockIdx.x * 128;

    if (tid < 128) {
        int c = tid;
        float s1v = g1[layer*D+c] * rsqrtf(v1[layer*D+c] + BN_EPS);
        sc1[c] = s1v; sh1[c] = be1[layer*D+c] - m1[layer*D+c] * s1v;
        bs1[c] = b1[layer*D+c];
        float s2v = g2[layer*D+c] * rsqrtf(v2[layer*D+c] + BN_EPS);
        sc2[c] = s2v; sh2[c] = be2[layer*D+c] - m2[layer*D+c] * s2v;
        bs2[c] = b2[layer*D+c];
    }

    // ---- stage bf16 U tile (pure copy, coalesced uint4) ----
#pragma unroll
    for (int i = 0; i < 8; ++i) {
        int slot = tid + 256 * i;        // 0..2047 = 128 rows x 16 chunks
        int r    = slot >> 4;
        int c8   = (slot & 15) << 3;
        int grow = row0 + r;
        uint4 q = make_uint4(0, 0, 0, 0);
        if (grow < N) q = *(const uint4*)(Uin + (size_t)grow * D + c8);
        *(uint4*)&Up[r][c8] = q;
    }
    __syncthreads();

    f32x4 acc0[8], acc1[8];
    const int col16 = lane & 15;
    const int quad  = lane >> 4;

    // ---- GEMM1 + ReLU + BN1, round to bf16 back into Up ----
    mfma_gemm32(Up, Wsw, layer * 4 + 0, bs1, m0, lane, acc0, acc1);
    __syncthreads();   // all A-reads of GEMM1 done before overwrite
#pragma unroll
    for (int nt = 0; nt < 8; ++nt) {
        int c = nt * 16 + col16;
        float s = sc1[c], t = sh1[c];
#pragma unroll
        for (int r = 0; r < 4; ++r) {
            Up[m0 + quad * 4 + r][c]      = f2bf_rn(fmaf(fmaxf(acc0[nt][r], 0.f), s, t));
            Up[m0 + 16 + quad * 4 + r][c] = f2bf_rn(fmaf(fmaxf(acc1[nt][r], 0.f), s, t));
        }
    }
    __syncthreads();

    // ---- GEMM2 + BN2 + ReLU, store (bf16 intermediate / fp32 final) ----
    mfma_gemm32(Up, Wsw, layer * 4 + 2, bs2, m0, lane, acc0, acc1);
#pragma unroll
    for (int nt = 0; nt < 8; ++nt) {
        int c = nt * 16 + col16;
        float s = sc2[c], t = sh2[c];
#pragma unroll
        for (int r = 0; r < 4; ++r) {
            int gr0 = row0 + m0 + quad * 4 + r;
            int gr1 = gr0 + 16;
            float o0 = fmaxf(fmaf(acc0[nt][r], s, t), 0.f);
            float o1 = fmaxf(fmaf(acc1[nt][r], s, t), 0.f);
            if (last) {
                if (gr0 < N) hout_f[(size_t)gr0 * D + c] = o0;
                if (gr1 < N) hout_f[(size_t)gr1 * D + c] = o1;
            } else {
                if (gr0 < N) hout_bf[(size_t)gr0 * D + c] = f2bf_rn(o0);
                if (gr1 < N) hout_bf[(size_t)gr1 * D + c] = f2bf_rn(o1);
            }
        }
    }
}

extern "C" void kernel_launch(void* const* d_in, const int* in_sizes, int n_in,
                              void* d_out, int out_size, void* d_ws, size_t ws_size,
                              hipStream_t stream)
{
    const float* x   = (const float*)d_in[0];
    const int*   ei  = (const int*)d_in[1];
    const float* W1  = (const float*)d_in[2];
    const float* b1  = (const float*)d_in[3];
    const float* g1  = (const float*)d_in[4];
    const float* be1 = (const float*)d_in[5];
    const float* m1  = (const float*)d_in[6];
    const float* v1  = (const float*)d_in[7];
    const float* W2  = (const float*)d_in[8];
    const float* b2  = (const float*)d_in[9];
    const float* eps = (const float*)d_in[10];
    const float* g2  = (const float*)d_in[11];
    const float* be2 = (const float*)d_in[12];
    const float* m2  = (const float*)d_in[13];
    const float* v2  = (const float*)d_in[14];

    const int N = in_sizes[0] / D;
    const int E = in_sizes[1] / 2;
    const int L = in_sizes[10];

    float*          out = (float*)d_out;
    unsigned short* hb  = (unsigned short*)d_out;   // bf16 h in d_out's first
                                                    // half; dead before the final
                                                    // fp32 write clobbers it

    // ws layout: U(bf16) | row_ptr | blk | fill_pos | col | Wsw  (~29 MB)
    unsigned short* U        = (unsigned short*)d_ws;
    int*            row_ptr  = (int*)(U + (size_t)N * D);
    int*            blk      = row_ptr + (N + 1);
    int*            fill_pos = blk + 2048;
    int*            col      = fill_pos + N;
    size_t off = (size_t)((char*)(col + E) - (char*)d_ws);
    off = (off + 255) & ~(size_t)255;
    unsigned short* Wsw = (unsigned short*)((char*)d_ws + off);

    const int* src = ei;
    const int* dst = ei + E;

    const int NB = (N + SCAN_CHUNK - 1) / SCAN_CHUNK;

    // ---- weight pre-split + CSR build (once per launch) ----
    const int wtot = L * 2 * 4 * 8 * 64;
    w_split<<<(wtot + 255) / 256, 256, 0, stream>>>(W1, W2, Wsw, wtot);
    hipMemsetAsync(row_ptr, 0, (size_t)(N + 1 + 2048 + N) * sizeof(int), stream);
    csr_hist<<<(E + 255) / 256, 256, 0, stream>>>(dst, row_ptr, E);
    scan_pass_a<<<NB, SCAN_TPB, 0, stream>>>(row_ptr, blk, N);
    scan_pass_b<<<1, SCAN_TPB, 0, stream>>>(blk, NB);
    scan_pass_c<<<NB, SCAN_TPB, 0, stream>>>(row_ptr, blk, N, E);
    csr_fill<<<(E + 255) / 256, 256, 0, stream>>>(src, dst, row_ptr, fill_pos, col, E);

    // ---- layers ----
    const int mlp_blocks = (N + 127) / 128;
    for (int l = 0; l < L; ++l) {
        if (l == 0)
            gin_gather_f32<<<(N + 7) / 8, 256, 0, stream>>>(x, row_ptr, col, eps, l, U, N);
        else
            gin_gather_bf16<<<(N + 15) / 16, 256, 0, stream>>>(hb, row_ptr, col, eps, l, U, N);
        gin_mlp_mfma<<<mlp_blocks, 256, 0, stream>>>(U, Wsw,
                                                     b1, g1, be1, m1, v1,
                                                     b2, g2, be2, m2, v2,
                                                     l, N, (l == L - 1) ? 1 : 0,
                                                     hb, out);
    }
}

// Round 8
// 532.943 us; speedup vs baseline: 10.7694x; 1.0844x over previous
//
#include <hip/hip_runtime.h>

#define D 128
#define BN_EPS 1e-5f
#define SCAN_TPB 256
#define SCAN_EPT 8
#define SCAN_CHUNK (SCAN_TPB * SCAN_EPT)

typedef __attribute__((ext_vector_type(8))) short bf16x8;
typedef __attribute__((ext_vector_type(4))) float f32x4;

__device__ __forceinline__ unsigned short f2bf_rn(float f) {
    unsigned u = __float_as_uint(f);
    u += 0x7FFFu + ((u >> 16) & 1u);
    return (unsigned short)(u >> 16);
}

// ---------------------------------------------------------------------------
// CSR build (once per launch).
// ---------------------------------------------------------------------------
__global__ __launch_bounds__(256) void csr_hist(
    const int* __restrict__ dst, int* __restrict__ deg, int E)
{
    int e = blockIdx.x * 256 + threadIdx.x;
    if (e < E) atomicAdd(&deg[dst[e]], 1);
}

__global__ __launch_bounds__(SCAN_TPB) void scan_pass_a(
    int* __restrict__ data, int* __restrict__ blk, int n)
{
    __shared__ int s[SCAN_TPB];
    int tid  = threadIdx.x;
    int base = blockIdx.x * SCAN_CHUNK + tid * SCAN_EPT;
    int v[SCAN_EPT];
    int sum = 0;
#pragma unroll
    for (int i = 0; i < SCAN_EPT; ++i) {
        v[i] = (base + i < n) ? data[base + i] : 0;
        sum += v[i];
    }
    s[tid] = sum;
    __syncthreads();
#pragma unroll
    for (int off = 1; off < SCAN_TPB; off <<= 1) {
        int t = (tid >= off) ? s[tid - off] : 0;
        __syncthreads();
        s[tid] += t;
        __syncthreads();
    }
    int run = s[tid] - sum;
#pragma unroll
    for (int i = 0; i < SCAN_EPT; ++i) {
        if (base + i < n) data[base + i] = run;
        run += v[i];
    }
    if (tid == SCAN_TPB - 1) blk[blockIdx.x] = s[SCAN_TPB - 1];
}

__global__ __launch_bounds__(SCAN_TPB) void scan_pass_b(
    int* __restrict__ data, int n)
{
    __shared__ int s[SCAN_TPB];
    int tid  = threadIdx.x;
    int base = tid * SCAN_EPT;
    int v[SCAN_EPT];
    int sum = 0;
#pragma unroll
    for (int i = 0; i < SCAN_EPT; ++i) {
        v[i] = (base + i < n) ? data[base + i] : 0;
        sum += v[i];
    }
    s[tid] = sum;
    __syncthreads();
#pragma unroll
    for (int off = 1; off < SCAN_TPB; off <<= 1) {
        int t = (tid >= off) ? s[tid - off] : 0;
        __syncthreads();
        s[tid] += t;
        __syncthreads();
    }
    int run = s[tid] - sum;
#pragma unroll
    for (int i = 0; i < SCAN_EPT; ++i) {
        if (base + i < n) data[base + i] = run;
        run += v[i];
    }
}

__global__ __launch_bounds__(SCAN_TPB) void scan_pass_c(
    int* __restrict__ data, const int* __restrict__ blk, int n, int E)
{
    int base = blockIdx.x * SCAN_CHUNK + threadIdx.x * SCAN_EPT;
    int add  = blk[blockIdx.x];
#pragma unroll
    for (int i = 0; i < SCAN_EPT; ++i)
        if (base + i < n) data[base + i] += add;
    if (blockIdx.x == 0 && threadIdx.x == 0) data[n] = E;
}

__global__ __launch_bounds__(256) void csr_fill(
    const int* __restrict__ src, const int* __restrict__ dst,
    const int* __restrict__ row_ptr, int* __restrict__ fill_pos,
    int* __restrict__ col, int E)
{
    int e = blockIdx.x * 256 + threadIdx.x;
    if (e < E) {
        int d   = dst[e];
        int pos = atomicAdd(&fill_pos[d], 1);
        col[row_ptr[d] + pos] = src[e];
    }
}

// ---------------------------------------------------------------------------
// Weight pre-split: fp32 W -> bf16 hi/lo in MFMA B-fragment order (layout
// verified rounds 4-7).
// ---------------------------------------------------------------------------
__global__ __launch_bounds__(256) void w_split(
    const float* __restrict__ W1, const float* __restrict__ W2,
    unsigned short* __restrict__ Wsw, int total)
{
    int t = blockIdx.x * 256 + threadIdx.x;
    if (t >= total) return;                 // total = L*2*4*8*64
    int lane = t & 63;
    int nt   = (t >> 6) & 7;
    int ks   = (t >> 9) & 3;
    int g    = t >> 11;
    int layer = g >> 1, gemm = g & 1;
    const float* W = (gemm ? W2 : W1) + (size_t)layer * D * D;
    int n  = nt * 16 + (lane & 15);
    int kb = ks * 32 + (lane >> 4) * 8;
    union { unsigned short s[8]; uint4 q; } uh, ul;
#pragma unroll
    for (int j = 0; j < 8; ++j) {
        float x = W[(size_t)(kb + j) * D + n];
        unsigned short h = f2bf_rn(x);
        float r = x - __uint_as_float((unsigned)h << 16);
        uh.s[j] = h;
        ul.s[j] = f2bf_rn(r);
    }
    size_t ehi = ((((size_t)g * 2 + 0) * 4 + ks) * 8 + nt) * 512 + (size_t)lane * 8;
    size_t elo = ((((size_t)g * 2 + 1) * 4 + ks) * 8 + nt) * 512 + (size_t)lane * 8;
    *(uint4*)&Wsw[ehi] = uh.q;
    *(uint4*)&Wsw[elo] = ul.q;
}

// ---------------------------------------------------------------------------
// One-time x (fp32) -> bf16 conversion, so all layers use the bf16 gather.
// ---------------------------------------------------------------------------
__global__ __launch_bounds__(256) void x2bf(
    const float* __restrict__ x, unsigned short* __restrict__ o, int n8)
{
    int i = blockIdx.x * 256 + threadIdx.x;   // 8-element group index
    if (i >= n8) return;
    const float4* p = (const float4*)(x + (size_t)i * 8);
    float4 v0 = p[0], v1 = p[1];
    union { unsigned short s[8]; uint4 q; } u;
    u.s[0] = f2bf_rn(v0.x); u.s[1] = f2bf_rn(v0.y);
    u.s[2] = f2bf_rn(v0.z); u.s[3] = f2bf_rn(v0.w);
    u.s[4] = f2bf_rn(v1.x); u.s[5] = f2bf_rn(v1.y);
    u.s[6] = f2bf_rn(v1.z); u.s[7] = f2bf_rn(v1.w);
    *((uint4*)o + i) = u.q;
}

// ---------------------------------------------------------------------------
// Gather (bf16 h): TWO rows per 16-lane group -> 16+ loads in flight.
// U[row] = (1+eps)*h[row] + sum_nbr h[col]. Branchless 8-deep batches with
// clamp+zero-weight predication; idle row streams use node 0 with weight 0.
// ---------------------------------------------------------------------------
__device__ __forceinline__ void acc_bf8(float a[8], uint4 q, float w) {
    a[0] = fmaf(w, __uint_as_float(q.x << 16), a[0]);
    a[1] = fmaf(w, __uint_as_float(q.x & 0xffff0000u), a[1]);
    a[2] = fmaf(w, __uint_as_float(q.y << 16), a[2]);
    a[3] = fmaf(w, __uint_as_float(q.y & 0xffff0000u), a[3]);
    a[4] = fmaf(w, __uint_as_float(q.z << 16), a[4]);
    a[5] = fmaf(w, __uint_as_float(q.z & 0xffff0000u), a[5]);
    a[6] = fmaf(w, __uint_as_float(q.w << 16), a[6]);
    a[7] = fmaf(w, __uint_as_float(q.w & 0xffff0000u), a[7]);
}

__global__ __launch_bounds__(256) void gin_gather_bf16(
    const unsigned short* __restrict__ h,
    const int* __restrict__ row_ptr, const int* __restrict__ col,
    const float* __restrict__ eps, int layer,
    unsigned short* __restrict__ U, int N)
{
    int grp = (blockIdx.x * 256 + threadIdx.x) >> 4;   // row-pair index
    int l16 = threadIdx.x & 15;
    int c8  = l16 << 3;
    int rA  = grp * 2;
    if (rA >= N) return;
    bool hasB = (rA + 1) < N;
    int rB = hasB ? rA + 1 : rA;

    const float epsv = 1.0f + eps[layer];
    float a0[8], a1[8];
    {
        uint4 qa = *(const uint4*)(h + (size_t)rA * D + c8);
        uint4 qb = *(const uint4*)(h + (size_t)rB * D + c8);
#pragma unroll
        for (int i = 0; i < 8; ++i) { a0[i] = 0.f; a1[i] = 0.f; }
        acc_bf8(a0, qa, epsv);
        acc_bf8(a1, qb, epsv);
    }

    int j0 = row_ptr[rA], e0 = row_ptr[rA + 1];
    int j1 = row_ptr[rB];
    int e1 = hasB ? row_ptr[rB + 1] : j1;

    while (j0 < e0 || j1 < e1) {
        int cnt0 = min(e0 - j0, 8);
        int cnt1 = min(e1 - j1, 8);
        int i0 = (cnt0 > 0) ? col[j0 + min(l16, cnt0 - 1)] : 0;
        int i1 = (cnt1 > 0) ? col[j1 + min(l16, cnt1 - 1)] : 0;
        uint4 t[8], u[8];
#pragma unroll
        for (int k = 0; k < 8; ++k) {
            int s0 = __shfl(i0, k, 16);
            t[k] = *(const uint4*)(h + (size_t)s0 * D + c8);
        }
#pragma unroll
        for (int k = 0; k < 8; ++k) {
            int s1 = __shfl(i1, k, 16);
            u[k] = *(const uint4*)(h + (size_t)s1 * D + c8);
        }
#pragma unroll
        for (int k = 0; k < 8; ++k) {
            float w0 = (k < cnt0) ? 1.f : 0.f;
            float w1 = (k < cnt1) ? 1.f : 0.f;
            acc_bf8(a0, t[k], w0);
            acc_bf8(a1, u[k], w1);
        }
        j0 += max(cnt0, 0);
        j1 += max(cnt1, 0);
    }

    union { unsigned short s[8]; uint4 q; } o0, o1;
#pragma unroll
    for (int i = 0; i < 8; ++i) { o0.s[i] = f2bf_rn(a0[i]); o1.s[i] = f2bf_rn(a1[i]); }
    *(uint4*)(U + (size_t)rA * D + c8) = o0.q;
    if (hasB) *(uint4*)(U + (size_t)rB * D + c8) = o1.q;
}

// ---------------------------------------------------------------------------
// MFMA MLP. Tile M=64 (1563 blocks -> ~6 blocks/CU), block = 4 waves, each
// wave owns ONE 16-row strip end-to-end -> strips disjoint, only 2 barriers
// (stage, pre-store). LDS 20.5 KB. bf16 output coalesced via LDS round-trip.
// ---------------------------------------------------------------------------
__device__ __forceinline__ void mfma_gemm16(
    const unsigned short (*Up)[136], const unsigned short* __restrict__ Wsw,
    int g2s_hi, const float* __restrict__ bsLDS,
    int m0, int lane, f32x4 acc[8])
{
    const int col16 = lane & 15;
    const int quad  = lane >> 4;
#pragma unroll
    for (int nt = 0; nt < 8; ++nt) {
        float b = bsLDS[nt * 16 + col16];
        acc[nt][0] = b; acc[nt][1] = b; acc[nt][2] = b; acc[nt][3] = b;
    }
    const int r0 = m0 + col16;
#pragma unroll
    for (int ks = 0; ks < 4; ++ks) {
        const int kb = ks * 32 + quad * 8;
        bf16x8 a0 = *(const bf16x8*)&Up[r0][kb];
        const unsigned short* whB =
            Wsw + ((((size_t)g2s_hi)     * 4 + ks) * 8) * 512 + (size_t)lane * 8;
        const unsigned short* wlB =
            Wsw + ((((size_t)g2s_hi + 1) * 4 + ks) * 8) * 512 + (size_t)lane * 8;
#pragma unroll
        for (int nt = 0; nt < 8; ++nt) {
            bf16x8 bh = *(const bf16x8*)(whB + (size_t)nt * 512);
            bf16x8 bl = *(const bf16x8*)(wlB + (size_t)nt * 512);
            acc[nt] = __builtin_amdgcn_mfma_f32_16x16x32_bf16(a0, bh, acc[nt], 0, 0, 0);
            acc[nt] = __builtin_amdgcn_mfma_f32_16x16x32_bf16(a0, bl, acc[nt], 0, 0, 0);
        }
    }
}

__global__ __launch_bounds__(256) void gin_mlp_mfma(
    const unsigned short* __restrict__ Uin,
    const unsigned short* __restrict__ Wsw,
    const float* __restrict__ b1, const float* __restrict__ g1,
    const float* __restrict__ be1, const float* __restrict__ m1,
    const float* __restrict__ v1,
    const float* __restrict__ b2, const float* __restrict__ g2,
    const float* __restrict__ be2, const float* __restrict__ m2,
    const float* __restrict__ v2,
    int layer, int N, int last,
    unsigned short* __restrict__ hout_bf, float* __restrict__ hout_f)
{
    __shared__ unsigned short Up[64][136];           // 17.4 KB bf16
    __shared__ float sc1[128], sh1[128], bs1[128];
    __shared__ float sc2[128], sh2[128], bs2[128];   // 3 KB

    const int tid  = threadIdx.x;
    const int lane = tid & 63;
    const int wv   = tid >> 6;
    const int m0   = wv * 16;
    const int row0 = blockIdx.x * 64;

    if (tid < 128) {
        int c = tid;
        float s1v = g1[layer*D+c] * rsqrtf(v1[layer*D+c] + BN_EPS);
        sc1[c] = s1v; sh1[c] = be1[layer*D+c] - m1[layer*D+c] * s1v;
        bs1[c] = b1[layer*D+c];
        float s2v = g2[layer*D+c] * rsqrtf(v2[layer*D+c] + BN_EPS);
        sc2[c] = s2v; sh2[c] = be2[layer*D+c] - m2[layer*D+c] * s2v;
        bs2[c] = b2[layer*D+c];
    }

    // ---- stage bf16 U tile: 64 rows x 16 uint4 chunks ----
#pragma unroll
    for (int i = 0; i < 4; ++i) {
        int slot = tid + 256 * i;
        int r    = slot >> 4;
        int c8   = (slot & 15) << 3;
        int grow = row0 + r;
        uint4 q = make_uint4(0, 0, 0, 0);
        if (grow < N) q = *(const uint4*)(Uin + (size_t)grow * D + c8);
        *(uint4*)&Up[r][c8] = q;
    }
    __syncthreads();

    f32x4 acc[8];
    const int col16 = lane & 15;
    const int quad  = lane >> 4;

    // ---- GEMM1 + ReLU + BN1 -> bf16 back into own strip (no barrier:
    //      each wave reads/writes only rows [m0, m0+16)) ----
    mfma_gemm16(Up, Wsw, layer * 4 + 0, bs1, m0, lane, acc);
#pragma unroll
    for (int nt = 0; nt < 8; ++nt) {
        int c = nt * 16 + col16;
        float s = sc1[c], t = sh1[c];
#pragma unroll
        for (int r = 0; r < 4; ++r)
            Up[m0 + quad * 4 + r][c] = f2bf_rn(fmaf(fmaxf(acc[nt][r], 0.f), s, t));
    }

    // ---- GEMM2 + BN2 + ReLU ----
    mfma_gemm16(Up, Wsw, layer * 4 + 2, bs2, m0, lane, acc);
    if (last) {
        // final fp32 output: direct stores (64B-contiguous per 16 lanes)
#pragma unroll
        for (int nt = 0; nt < 8; ++nt) {
            int c = nt * 16 + col16;
            float s = sc2[c], t = sh2[c];
#pragma unroll
            for (int r = 0; r < 4; ++r) {
                int grow = row0 + m0 + quad * 4 + r;
                if (grow < N)
                    hout_f[(size_t)grow * D + c] = fmaxf(fmaf(acc[nt][r], s, t), 0.f);
            }
        }
    } else {
        // bf16 intermediate: LDS round-trip -> fully coalesced uint4 stores
#pragma unroll
        for (int nt = 0; nt < 8; ++nt) {
            int c = nt * 16 + col16;
            float s = sc2[c], t = sh2[c];
#pragma unroll
            for (int r = 0; r < 4; ++r)
                Up[m0 + quad * 4 + r][c] = f2bf_rn(fmaxf(fmaf(acc[nt][r], s, t), 0.f));
        }
        __syncthreads();
#pragma unroll
        for (int i = 0; i < 4; ++i) {
            int slot = tid + 256 * i;
            int r    = slot >> 4;
            int c8   = (slot & 15) << 3;
            int grow = row0 + r;
            if (grow < N)
                *(uint4*)(hout_bf + (size_t)grow * D + c8) = *(const uint4*)&Up[r][c8];
        }
    }
}

extern "C" void kernel_launch(void* const* d_in, const int* in_sizes, int n_in,
                              void* d_out, int out_size, void* d_ws, size_t ws_size,
                              hipStream_t stream)
{
    const float* x   = (const float*)d_in[0];
    const int*   ei  = (const int*)d_in[1];
    const float* W1  = (const float*)d_in[2];
    const float* b1  = (const float*)d_in[3];
    const float* g1  = (const float*)d_in[4];
    const float* be1 = (const float*)d_in[5];
    const float* m1  = (const float*)d_in[6];
    const float* v1  = (const float*)d_in[7];
    const float* W2  = (const float*)d_in[8];
    const float* b2  = (const float*)d_in[9];
    const float* eps = (const float*)d_in[10];
    const float* g2  = (const float*)d_in[11];
    const float* be2 = (const float*)d_in[12];
    const float* m2  = (const float*)d_in[13];
    const float* v2  = (const float*)d_in[14];

    const int N = in_sizes[0] / D;
    const int E = in_sizes[1] / 2;
    const int L = in_sizes[10];

    float*          out = (float*)d_out;
    unsigned short* hb  = (unsigned short*)d_out;   // bf16 h in d_out's first
                                                    // half; dead before the final
                                                    // fp32 write clobbers it

    // ws layout: U(bf16) | row_ptr | blk | fill_pos | col | Wsw  (~29 MB)
    unsigned short* U        = (unsigned short*)d_ws;
    int*            row_ptr  = (int*)(U + (size_t)N * D);
    int*            blk      = row_ptr + (N + 1);
    int*            fill_pos = blk + 2048;
    int*            col      = fill_pos + N;
    size_t off = (size_t)((char*)(col + E) - (char*)d_ws);
    off = (off + 255) & ~(size_t)255;
    unsigned short* Wsw = (unsigned short*)((char*)d_ws + off);

    const int* src = ei;
    const int* dst = ei + E;

    const int NB = (N + SCAN_CHUNK - 1) / SCAN_CHUNK;

    // ---- one-time prep: weight split, CSR build, x -> bf16 ----
    const int wtot = L * 2 * 4 * 8 * 64;
    w_split<<<(wtot + 255) / 256, 256, 0, stream>>>(W1, W2, Wsw, wtot);
    hipMemsetAsync(row_ptr, 0, (size_t)(N + 1 + 2048 + N) * sizeof(int), stream);
    csr_hist<<<(E + 255) / 256, 256, 0, stream>>>(dst, row_ptr, E);
    scan_pass_a<<<NB, SCAN_TPB, 0, stream>>>(row_ptr, blk, N);
    scan_pass_b<<<1, SCAN_TPB, 0, stream>>>(blk, NB);
    scan_pass_c<<<NB, SCAN_TPB, 0, stream>>>(row_ptr, blk, N, E);
    csr_fill<<<(E + 255) / 256, 256, 0, stream>>>(src, dst, row_ptr, fill_pos, col, E);
    const int n8 = N * D / 8;
    x2bf<<<(n8 + 255) / 256, 256, 0, stream>>>(x, hb, n8);

    // ---- layers ----
    const int gat_blocks = (N + 31) / 32;    // 2 rows per 16-lane group
    const int mlp_blocks = (N + 63) / 64;
    for (int l = 0; l < L; ++l) {
        gin_gather_bf16<<<gat_blocks, 256, 0, stream>>>(hb, row_ptr, col, eps, l, U, N);
        gin_mlp_mfma<<<mlp_blocks, 256, 0, stream>>>(U, Wsw,
                                                     b1, g1, be1, m1, v1,
                                                     b2, g2, be2, m2, v2,
                                                     l, N, (l == L - 1) ? 1 : 0,
                                                     hb, out);
    }
}

// Round 9
// 470.962 us; speedup vs baseline: 12.1867x; 1.1316x over previous
//
#include <hip/hip_runtime.h>

#define D 128
#define BN_EPS 1e-5f
#define SCAN_TPB 256
#define SCAN_EPT 8
#define SCAN_CHUNK (SCAN_TPB * SCAN_EPT)

typedef __attribute__((ext_vector_type(8))) short bf16x8;
typedef __attribute__((ext_vector_type(4))) float f32x4;

__device__ __forceinline__ unsigned short f2bf_rn(float f) {
    unsigned u = __float_as_uint(f);
    u += 0x7FFFu + ((u >> 16) & 1u);
    return (unsigned short)(u >> 16);
}

// ---------------------------------------------------------------------------
// CSR build (once per launch).
// ---------------------------------------------------------------------------
__global__ __launch_bounds__(256) void csr_hist(
    const int* __restrict__ dst, int* __restrict__ deg, int E)
{
    int e = blockIdx.x * 256 + threadIdx.x;
    if (e < E) atomicAdd(&deg[dst[e]], 1);
}

__global__ __launch_bounds__(SCAN_TPB) void scan_pass_a(
    int* __restrict__ data, int* __restrict__ blk, int n)
{
    __shared__ int s[SCAN_TPB];
    int tid  = threadIdx.x;
    int base = blockIdx.x * SCAN_CHUNK + tid * SCAN_EPT;
    int v[SCAN_EPT];
    int sum = 0;
#pragma unroll
    for (int i = 0; i < SCAN_EPT; ++i) {
        v[i] = (base + i < n) ? data[base + i] : 0;
        sum += v[i];
    }
    s[tid] = sum;
    __syncthreads();
#pragma unroll
    for (int off = 1; off < SCAN_TPB; off <<= 1) {
        int t = (tid >= off) ? s[tid - off] : 0;
        __syncthreads();
        s[tid] += t;
        __syncthreads();
    }
    int run = s[tid] - sum;
#pragma unroll
    for (int i = 0; i < SCAN_EPT; ++i) {
        if (base + i < n) data[base + i] = run;
        run += v[i];
    }
    if (tid == SCAN_TPB - 1) blk[blockIdx.x] = s[SCAN_TPB - 1];
}

__global__ __launch_bounds__(SCAN_TPB) void scan_pass_b(
    int* __restrict__ data, int n)
{
    __shared__ int s[SCAN_TPB];
    int tid  = threadIdx.x;
    int base = tid * SCAN_EPT;
    int v[SCAN_EPT];
    int sum = 0;
#pragma unroll
    for (int i = 0; i < SCAN_EPT; ++i) {
        v[i] = (base + i < n) ? data[base + i] : 0;
        sum += v[i];
    }
    s[tid] = sum;
    __syncthreads();
#pragma unroll
    for (int off = 1; off < SCAN_TPB; off <<= 1) {
        int t = (tid >= off) ? s[tid - off] : 0;
        __syncthreads();
        s[tid] += t;
        __syncthreads();
    }
    int run = s[tid] - sum;
#pragma unroll
    for (int i = 0; i < SCAN_EPT; ++i) {
        if (base + i < n) data[base + i] = run;
        run += v[i];
    }
}

__global__ __launch_bounds__(SCAN_TPB) void scan_pass_c(
    int* __restrict__ data, const int* __restrict__ blk, int n, int E)
{
    int base = blockIdx.x * SCAN_CHUNK + threadIdx.x * SCAN_EPT;
    int add  = blk[blockIdx.x];
#pragma unroll
    for (int i = 0; i < SCAN_EPT; ++i)
        if (base + i < n) data[base + i] += add;
    if (blockIdx.x == 0 && threadIdx.x == 0) data[n] = E;
}

__global__ __launch_bounds__(256) void csr_fill(
    const int* __restrict__ src, const int* __restrict__ dst,
    const int* __restrict__ row_ptr, int* __restrict__ fill_pos,
    int* __restrict__ col, int E)
{
    int e = blockIdx.x * 256 + threadIdx.x;
    if (e < E) {
        int d   = dst[e];
        int pos = atomicAdd(&fill_pos[d], 1);
        col[row_ptr[d] + pos] = src[e];
    }
}

// ---------------------------------------------------------------------------
// Weight pre-split: fp32 W -> bf16 hi/lo in MFMA B-fragment order (layout
// verified rounds 4-8).
// ---------------------------------------------------------------------------
__global__ __launch_bounds__(256) void w_split(
    const float* __restrict__ W1, const float* __restrict__ W2,
    unsigned short* __restrict__ Wsw, int total)
{
    int t = blockIdx.x * 256 + threadIdx.x;
    if (t >= total) return;                 // total = L*2*4*8*64
    int lane = t & 63;
    int nt   = (t >> 6) & 7;
    int ks   = (t >> 9) & 3;
    int g    = t >> 11;
    int layer = g >> 1, gemm = g & 1;
    const float* W = (gemm ? W2 : W1) + (size_t)layer * D * D;
    int n  = nt * 16 + (lane & 15);
    int kb = ks * 32 + (lane >> 4) * 8;
    union { unsigned short s[8]; uint4 q; } uh, ul;
#pragma unroll
    for (int j = 0; j < 8; ++j) {
        float x = W[(size_t)(kb + j) * D + n];
        unsigned short h = f2bf_rn(x);
        float r = x - __uint_as_float((unsigned)h << 16);
        uh.s[j] = h;
        ul.s[j] = f2bf_rn(r);
    }
    size_t ehi = ((((size_t)g * 2 + 0) * 4 + ks) * 8 + nt) * 512 + (size_t)lane * 8;
    size_t elo = ((((size_t)g * 2 + 1) * 4 + ks) * 8 + nt) * 512 + (size_t)lane * 8;
    *(uint4*)&Wsw[ehi] = uh.q;
    *(uint4*)&Wsw[elo] = ul.q;
}

// ---------------------------------------------------------------------------
// One-time x (fp32) -> bf16.
// ---------------------------------------------------------------------------
__global__ __launch_bounds__(256) void x2bf(
    const float* __restrict__ x, unsigned short* __restrict__ o, int n8)
{
    int i = blockIdx.x * 256 + threadIdx.x;
    if (i >= n8) return;
    const float4* p = (const float4*)(x + (size_t)i * 8);
    float4 v0 = p[0], v1 = p[1];
    union { unsigned short s[8]; uint4 q; } u;
    u.s[0] = f2bf_rn(v0.x); u.s[1] = f2bf_rn(v0.y);
    u.s[2] = f2bf_rn(v0.z); u.s[3] = f2bf_rn(v0.w);
    u.s[4] = f2bf_rn(v1.x); u.s[5] = f2bf_rn(v1.y);
    u.s[6] = f2bf_rn(v1.z); u.s[7] = f2bf_rn(v1.w);
    *((uint4*)o + i) = u.q;
}

// ---------------------------------------------------------------------------
// Gather (bf16 h): two rows per 16-lane group (unchanged from round 8).
// ---------------------------------------------------------------------------
__device__ __forceinline__ void acc_bf8(float a[8], uint4 q, float w) {
    a[0] = fmaf(w, __uint_as_float(q.x << 16), a[0]);
    a[1] = fmaf(w, __uint_as_float(q.x & 0xffff0000u), a[1]);
    a[2] = fmaf(w, __uint_as_float(q.y << 16), a[2]);
    a[3] = fmaf(w, __uint_as_float(q.y & 0xffff0000u), a[3]);
    a[4] = fmaf(w, __uint_as_float(q.z << 16), a[4]);
    a[5] = fmaf(w, __uint_as_float(q.z & 0xffff0000u), a[5]);
    a[6] = fmaf(w, __uint_as_float(q.w << 16), a[6]);
    a[7] = fmaf(w, __uint_as_float(q.w & 0xffff0000u), a[7]);
}

__global__ __launch_bounds__(256) void gin_gather_bf16(
    const unsigned short* __restrict__ h,
    const int* __restrict__ row_ptr, const int* __restrict__ col,
    const float* __restrict__ eps, int layer,
    unsigned short* __restrict__ U, int N)
{
    int grp = (blockIdx.x * 256 + threadIdx.x) >> 4;
    int l16 = threadIdx.x & 15;
    int c8  = l16 << 3;
    int rA  = grp * 2;
    if (rA >= N) return;
    bool hasB = (rA + 1) < N;
    int rB = hasB ? rA + 1 : rA;

    const float epsv = 1.0f + eps[layer];
    float a0[8], a1[8];
    {
        uint4 qa = *(const uint4*)(h + (size_t)rA * D + c8);
        uint4 qb = *(const uint4*)(h + (size_t)rB * D + c8);
#pragma unroll
        for (int i = 0; i < 8; ++i) { a0[i] = 0.f; a1[i] = 0.f; }
        acc_bf8(a0, qa, epsv);
        acc_bf8(a1, qb, epsv);
    }

    int j0 = row_ptr[rA], e0 = row_ptr[rA + 1];
    int j1 = row_ptr[rB];
    int e1 = hasB ? row_ptr[rB + 1] : j1;

    while (j0 < e0 || j1 < e1) {
        int cnt0 = min(e0 - j0, 8);
        int cnt1 = min(e1 - j1, 8);
        int i0 = (cnt0 > 0) ? col[j0 + min(l16, cnt0 - 1)] : 0;
        int i1 = (cnt1 > 0) ? col[j1 + min(l16, cnt1 - 1)] : 0;
        uint4 t[8], u[8];
#pragma unroll
        for (int k = 0; k < 8; ++k) {
            int s0 = __shfl(i0, k, 16);
            t[k] = *(const uint4*)(h + (size_t)s0 * D + c8);
        }
#pragma unroll
        for (int k = 0; k < 8; ++k) {
            int s1 = __shfl(i1, k, 16);
            u[k] = *(const uint4*)(h + (size_t)s1 * D + c8);
        }
#pragma unroll
        for (int k = 0; k < 8; ++k) {
            float w0 = (k < cnt0) ? 1.f : 0.f;
            float w1 = (k < cnt1) ? 1.f : 0.f;
            acc_bf8(a0, t[k], w0);
            acc_bf8(a1, u[k], w1);
        }
        j0 += max(cnt0, 0);
        j1 += max(cnt1, 0);
    }

    union { unsigned short s[8]; uint4 q; } o0, o1;
#pragma unroll
    for (int i = 0; i < 8; ++i) { o0.s[i] = f2bf_rn(a0[i]); o1.s[i] = f2bf_rn(a1[i]); }
    *(uint4*)(U + (size_t)rA * D + c8) = o0.q;
    if (hasB) *(uint4*)(U + (size_t)rB * D + c8) = o1.q;
}

// ---------------------------------------------------------------------------
// MFMA MLP, N-split waves. Tile M=64; each of 4 waves computes ALL 64 rows
// for ITS 32 columns (nt pair). Per-wave B traffic drops 4x (16 KB/GEMM);
// each B-frag feeds 8 MFMAs. A-frags from LDS (ds_read_b128, 4 strips).
// Accumulators: 4 strips x 2 nt x f32x4 = 32 VGPRs.
// ---------------------------------------------------------------------------
__device__ __forceinline__ void mfma_gemm_nsplit(
    const unsigned short (*Up)[136], const unsigned short* __restrict__ Wsw,
    int g2s_hi, const float* __restrict__ bsLDS,
    int nt0, int lane, f32x4 acc[4][2])
{
    const int col16 = lane & 15;
    const int quad  = lane >> 4;
#pragma unroll
    for (int nl = 0; nl < 2; ++nl) {
        float b = bsLDS[(nt0 + nl) * 16 + col16];
#pragma unroll
        for (int st = 0; st < 4; ++st) {
            acc[st][nl][0] = b; acc[st][nl][1] = b;
            acc[st][nl][2] = b; acc[st][nl][3] = b;
        }
    }
#pragma unroll
    for (int ks = 0; ks < 4; ++ks) {
        const int kb = ks * 32 + quad * 8;
        bf16x8 a[4];
#pragma unroll
        for (int st = 0; st < 4; ++st)
            a[st] = *(const bf16x8*)&Up[st * 16 + col16][kb];
        const unsigned short* whB =
            Wsw + ((((size_t)g2s_hi)     * 4 + ks) * 8) * 512 + (size_t)lane * 8;
        const unsigned short* wlB =
            Wsw + ((((size_t)g2s_hi + 1) * 4 + ks) * 8) * 512 + (size_t)lane * 8;
#pragma unroll
        for (int nl = 0; nl < 2; ++nl) {
            int nt = nt0 + nl;
            bf16x8 bh = *(const bf16x8*)(whB + (size_t)nt * 512);
            bf16x8 bl = *(const bf16x8*)(wlB + (size_t)nt * 512);
#pragma unroll
            for (int st = 0; st < 4; ++st) {
                acc[st][nl] = __builtin_amdgcn_mfma_f32_16x16x32_bf16(a[st], bh, acc[st][nl], 0, 0, 0);
                acc[st][nl] = __builtin_amdgcn_mfma_f32_16x16x32_bf16(a[st], bl, acc[st][nl], 0, 0, 0);
            }
        }
    }
}

__global__ __launch_bounds__(256) void gin_mlp_mfma(
    const unsigned short* __restrict__ Uin,
    const unsigned short* __restrict__ Wsw,
    const float* __restrict__ b1, const float* __restrict__ g1,
    const float* __restrict__ be1, const float* __restrict__ m1,
    const float* __restrict__ v1,
    const float* __restrict__ b2, const float* __restrict__ g2,
    const float* __restrict__ be2, const float* __restrict__ m2,
    const float* __restrict__ v2,
    int layer, int N, int last,
    unsigned short* __restrict__ hout_bf, float* __restrict__ hout_f)
{
    __shared__ unsigned short Up[64][136];           // 17.4 KB bf16
    __shared__ float sc1[128], sh1[128], bs1[128];
    __shared__ float sc2[128], sh2[128], bs2[128];   // 3 KB

    const int tid  = threadIdx.x;
    const int lane = tid & 63;
    const int wv   = tid >> 6;
    const int nt0  = wv * 2;                          // this wave's nt pair
    const int row0 = blockIdx.x * 64;

    if (tid < 128) {
        int c = tid;
        float s1v = g1[layer*D+c] * rsqrtf(v1[layer*D+c] + BN_EPS);
        sc1[c] = s1v; sh1[c] = be1[layer*D+c] - m1[layer*D+c] * s1v;
        bs1[c] = b1[layer*D+c];
        float s2v = g2[layer*D+c] * rsqrtf(v2[layer*D+c] + BN_EPS);
        sc2[c] = s2v; sh2[c] = be2[layer*D+c] - m2[layer*D+c] * s2v;
        bs2[c] = b2[layer*D+c];
    }

    // ---- stage bf16 U tile: 64 rows x 16 uint4 chunks ----
#pragma unroll
    for (int i = 0; i < 4; ++i) {
        int slot = tid + 256 * i;
        int r    = slot >> 4;
        int c8   = (slot & 15) << 3;
        int grow = row0 + r;
        uint4 q = make_uint4(0, 0, 0, 0);
        if (grow < N) q = *(const uint4*)(Uin + (size_t)grow * D + c8);
        *(uint4*)&Up[r][c8] = q;
    }
    __syncthreads();

    f32x4 acc[4][2];
    const int col16 = lane & 15;
    const int quad  = lane >> 4;

    // ---- GEMM1 (all rows, own cols) ----
    mfma_gemm_nsplit(Up, Wsw, layer * 4 + 0, bs1, nt0, lane, acc);
    __syncthreads();                                  // all A-reads done
    // ReLU+BN1, bf16 repack into own columns of Up
#pragma unroll
    for (int nl = 0; nl < 2; ++nl) {
        int c = (nt0 + nl) * 16 + col16;
        float s = sc1[c], t = sh1[c];
#pragma unroll
        for (int st = 0; st < 4; ++st)
#pragma unroll
            for (int r = 0; r < 4; ++r)
                Up[st * 16 + quad * 4 + r][c] =
                    f2bf_rn(fmaf(fmaxf(acc[st][nl][r], 0.f), s, t));
    }
    __syncthreads();                                  // repack visible to all

    // ---- GEMM2 + BN2 + ReLU ----
    mfma_gemm_nsplit(Up, Wsw, layer * 4 + 2, bs2, nt0, lane, acc);
    if (last) {
#pragma unroll
        for (int nl = 0; nl < 2; ++nl) {
            int c = (nt0 + nl) * 16 + col16;
            float s = sc2[c], t = sh2[c];
#pragma unroll
            for (int st = 0; st < 4; ++st)
#pragma unroll
                for (int r = 0; r < 4; ++r) {
                    int grow = row0 + st * 16 + quad * 4 + r;
                    if (grow < N)
                        hout_f[(size_t)grow * D + c] =
                            fmaxf(fmaf(acc[st][nl][r], s, t), 0.f);
                }
        }
    } else {
        __syncthreads();                              // GEMM2 A-reads done
#pragma unroll
        for (int nl = 0; nl < 2; ++nl) {
            int c = (nt0 + nl) * 16 + col16;
            float s = sc2[c], t = sh2[c];
#pragma unroll
            for (int st = 0; st < 4; ++st)
#pragma unroll
                for (int r = 0; r < 4; ++r)
                    Up[st * 16 + quad * 4 + r][c] =
                        f2bf_rn(fmaxf(fmaf(acc[st][nl][r], s, t), 0.f));
        }
        __syncthreads();
#pragma unroll
        for (int i = 0; i < 4; ++i) {
            int slot = tid + 256 * i;
            int r    = slot >> 4;
            int c8   = (slot & 15) << 3;
            int grow = row0 + r;
            if (grow < N)
                *(uint4*)(hout_bf + (size_t)grow * D + c8) = *(const uint4*)&Up[r][c8];
        }
    }
}

extern "C" void kernel_launch(void* const* d_in, const int* in_sizes, int n_in,
                              void* d_out, int out_size, void* d_ws, size_t ws_size,
                              hipStream_t stream)
{
    const float* x   = (const float*)d_in[0];
    const int*   ei  = (const int*)d_in[1];
    const float* W1  = (const float*)d_in[2];
    const float* b1  = (const float*)d_in[3];
    const float* g1  = (const float*)d_in[4];
    const float* be1 = (const float*)d_in[5];
    const float* m1  = (const float*)d_in[6];
    const float* v1  = (const float*)d_in[7];
    const float* W2  = (const float*)d_in[8];
    const float* b2  = (const float*)d_in[9];
    const float* eps = (const float*)d_in[10];
    const float* g2  = (const float*)d_in[11];
    const float* be2 = (const float*)d_in[12];
    const float* m2  = (const float*)d_in[13];
    const float* v2  = (const float*)d_in[14];

    const int N = in_sizes[0] / D;
    const int E = in_sizes[1] / 2;
    const int L = in_sizes[10];

    float*          out = (float*)d_out;
    unsigned short* hb  = (unsigned short*)d_out;   // bf16 h in d_out's first
                                                    // half; dead before final
                                                    // fp32 write clobbers it

    // ws layout: U(bf16) | row_ptr | blk | fill_pos | col | Wsw  (~29 MB)
    unsigned short* U        = (unsigned short*)d_ws;
    int*            row_ptr  = (int*)(U + (size_t)N * D);
    int*            blk      = row_ptr + (N + 1);
    int*            fill_pos = blk + 2048;
    int*            col      = fill_pos + N;
    size_t off = (size_t)((char*)(col + E) - (char*)d_ws);
    off = (off + 255) & ~(size_t)255;
    unsigned short* Wsw = (unsigned short*)((char*)d_ws + off);

    const int* src = ei;
    const int* dst = ei + E;

    const int NB = (N + SCAN_CHUNK - 1) / SCAN_CHUNK;

    // ---- one-time prep: weight split, CSR build, x -> bf16 ----
    const int wtot = L * 2 * 4 * 8 * 64;
    w_split<<<(wtot + 255) / 256, 256, 0, stream>>>(W1, W2, Wsw, wtot);
    hipMemsetAsync(row_ptr, 0, (size_t)(N + 1 + 2048 + N) * sizeof(int), stream);
    csr_hist<<<(E + 255) / 256, 256, 0, stream>>>(dst, row_ptr, E);
    scan_pass_a<<<NB, SCAN_TPB, 0, stream>>>(row_ptr, blk, N);
    scan_pass_b<<<1, SCAN_TPB, 0, stream>>>(blk, NB);
    scan_pass_c<<<NB, SCAN_TPB, 0, stream>>>(row_ptr, blk, N, E);
    csr_fill<<<(E + 255) / 256, 256, 0, stream>>>(src, dst, row_ptr, fill_pos, col, E);
    const int n8 = N * D / 8;
    x2bf<<<(n8 + 255) / 256, 256, 0, stream>>>(x, hb, n8);

    // ---- layers ----
    const int gat_blocks = (N + 31) / 32;
    const int mlp_blocks = (N + 63) / 64;
    for (int l = 0; l < L; ++l) {
        gin_gather_bf16<<<gat_blocks, 256, 0, stream>>>(hb, row_ptr, col, eps, l, U, N);
        gin_mlp_mfma<<<mlp_blocks, 256, 0, stream>>>(U, Wsw,
                                                     b1, g1, be1, m1, v1,
                                                     b2, g2, be2, m2, v2,
                                                     l, N, (l == L - 1) ? 1 : 0,
                                                     hb, out);
    }
}